// Round 4
// baseline (614.269 us; speedup 1.0000x reference)
//
#include <hip/hip_runtime.h>

typedef unsigned short u16;
typedef unsigned int u32;

#define Bb 2
#define Lc 2048
#define Dc 2048
#define Hc 16
#define DhC 128

typedef __bf16 bf16x8 __attribute__((ext_vector_type(8)));
typedef float f32x4 __attribute__((ext_vector_type(4)));
typedef float f32x16 __attribute__((ext_vector_type(16)));

__device__ __forceinline__ u16 f2b(float f) {
  u32 u = __float_as_uint(f);
  u32 r = (u + 0x7fffu + ((u >> 16) & 1u)) >> 16;
  return (u16)r;
}
__device__ __forceinline__ float b2f(u16 u) {
  return __uint_as_float(((u32)u) << 16);
}

// pack 2 f32 -> 1 u32 of 2 bf16 (lo in low half) -- T12 recipe, no builtin
__device__ __forceinline__ u32 cvtpk(float lo, float hi) {
  u32 r;
  asm("v_cvt_pk_bf16_f32 %0, %1, %2" : "=v"(r) : "v"(lo), "v"(hi));
  return r;
}

// async global->LDS DMA, 16B/lane; LDS dest = wave-uniform base + lane*16
__device__ __forceinline__ void gll16(const void* g, void* l) {
  __builtin_amdgcn_global_load_lds(
      (const __attribute__((address_space(1))) u32*)g,
      (__attribute__((address_space(3))) u32*)l, 16, 0, 0);
}

// ---------------------------------------------------------------------------
// Dtype sniffer + x canonicalize (kept; inputs verified bf16-compatible r4).
// ---------------------------------------------------------------------------
__global__ __launch_bounds__(256) void sniff_dtype(const u16* __restrict__ x,
                                                   int* __restrict__ flag) {
  __shared__ int bad;
  if (threadIdx.x == 0) bad = 0;
  __syncthreads();
  int local = 0;
  for (int i = threadIdx.x; i < 65536; i += 256) {
    float v = fabsf(b2f(x[i]));
    if (!(v < 1000.f)) local = 1;
  }
  if (local) atomicOr(&bad, 1);
  __syncthreads();
  if (threadIdx.x == 0) *flag = bad;
}

__global__ __launch_bounds__(256) void conv_x(const void* __restrict__ in,
                                              u16* __restrict__ out,
                                              const int* __restrict__ flag) {
  const int f32 = *flag;
  const int i0 = (blockIdx.x * 256 + threadIdx.x) * 4;
  if (f32) {
    const float* p = (const float*)in;
#pragma unroll
    for (int j = 0; j < 4; j++) out[i0 + j] = f2b(p[i0 + j]);
  } else {
    const u16* p = (const u16*)in;
#pragma unroll
    for (int j = 0; j < 4; j++) out[i0 + j] = p[i0 + j];
  }
}

// ---------------------------------------------------------------------------
// 2048x2048 transpose with dtype conversion (weights -> bf16 W^T).
// ---------------------------------------------------------------------------
__global__ __launch_bounds__(256) void transpose2d_conv(const void* __restrict__ in,
                                                        u16* __restrict__ out,
                                                        const int* __restrict__ flag) {
  __shared__ __align__(16) u16 tile[64][65];
  const int f32 = *flag;
  const int r0 = blockIdx.y * 64, c0 = blockIdx.x * 64;
  const int tc = threadIdx.x & 63, tr4 = threadIdx.x >> 6;
#pragma unroll
  for (int p = 0; p < 16; p++) {
    int r = tr4 + p * 4;
    size_t idx = (size_t)(r0 + r) * 2048 + c0 + tc;
    tile[r][tc] = f32 ? f2b(((const float*)in)[idx]) : ((const u16*)in)[idx];
  }
  __syncthreads();
#pragma unroll
  for (int p = 0; p < 16; p++) {
    int rr = tr4 + p * 4;
    out[(size_t)(c0 + rr) * 2048 + r0 + tc] = tile[tc][rr];
  }
}

// ---------------------------------------------------------------------------
// GEMM r10: 128x256 tile, BK=32, FRAGMENT-ORDER LDS (zero bank conflict),
// 4-slot ring, ONE barrier + ONE counted vmcnt per K-tile, setprio, XCD swz.
//
//  Fragment-order LDS: each 16-row x 32-col subtile (1 KB) is stored so that
//  read-lane l's fragment (row l&15, k-chunk l>>4) sits at subtile_base+l*16.
//  - staging: gll16 with per-lane global src A[st*16+(l&15)][k0+(l>>4)*8];
//    LDS dest linear (DMA-legal). Source perm == read perm (rule #21).
//  - fragment ds_read_b128 = wave-uniform base + lane*16: contiguous 1 KB,
//    ZERO conflicts (r9's row-major layout was a 4-way conflict: 9.4M cycles).
//  8 waves (2M x 4N), per-wave 64x64 = acc[4][4]. Grid: Mtiles=32 fixed;
//  QKV: 32x24=768 blocks (3 exact CU-rounds); Wo: 32x8=256 (1 exact round --
//  r9's 128-block Wo used half the machine).
//  Ring: iter t computes slot t&3, stages tile t+3 into slot (t+3)&3 (freed
//  at end of iter t-1 -- barrier-protected). 3 gll16/wave/tile; end-of-iter
//  vmcnt(6) leaves {t+2,t+3} in flight, confirms t+1. Never 0 in main loop.
//  LDS 96 KiB (A 4x8K + B 4x16K) -> 1 block/CU.
//  C col n: (n>>11) selects output buffer (stride bufStride) for fused QKV.
// ---------------------------------------------------------------------------
template <typename OutT>
__device__ __forceinline__ void gemmfo_core(const u16* __restrict__ A,
                                            const u16* __restrict__ Bt,
                                            OutT* __restrict__ C,
                                            int Ntiles, size_t bufStride) {
  constexpr int K = 2048;
  constexpr int NTK = K / 32;  // 64 K-tiles
  __shared__ __align__(16) u16 Als[4][128 * 32];
  __shared__ __align__(16) u16 Bls[4][256 * 32];

  const int tid = threadIdx.x;
  const int lane = tid & 63, w = tid >> 6;
  const int quad = lane >> 4, l15 = lane & 15;
  const int wm = w >> 2, wn = w & 3;  // 2M x 4N waves, per-wave 64x64

  // XCD-chunked bijective swizzle (nwg % 8 == 0: 768 and 256)
  const int nwg = 32 * Ntiles;
  const int q8 = nwg >> 3;
  const int id = (int)blockIdx.x;
  const int swz = (id & 7) * q8 + (id >> 3);
  const int m0 = (swz & 31) * 128;   // Mtiles = 32 always (M = 4096)
  const int n0 = (swz >> 5) * 256;

  // fragment-order staging sources: lane l covers (row l&15, k-chunk l>>4)
  const int sc = (lane >> 4) * 8;
  const u16* aSrc = A + (size_t)(m0 + w * 16 + l15) * K + sc;            // A subtile w
  const u16* bSrc0 = Bt + (size_t)(n0 + (2 * w) * 16 + l15) * K + sc;    // B subtile 2w
  const u16* bSrc1 = Bt + (size_t)(n0 + (2 * w + 1) * 16 + l15) * K + sc;

  const f32x4 fz = {0.f, 0.f, 0.f, 0.f};
  f32x4 acc[4][4];
#pragma unroll
  for (int i = 0; i < 4; i++)
#pragma unroll
    for (int j = 0; j < 4; j++) acc[i][j] = fz;

  auto stage = [&](int t) {
    const int s = t & 3;
    const int k = t * 32;
    gll16(aSrc + k, &Als[s][w * 512]);
    gll16(bSrc0 + k, &Bls[s][(2 * w) * 512]);
    gll16(bSrc1 + k, &Bls[s][(2 * w + 1) * 512]);
  };

  auto compute = [&](int t) {
    const u16* abuf = Als[t & 3];
    const u16* bbuf = Bls[t & 3];
    bf16x8 afr[4], bfr[4];
#pragma unroll
    for (int mt = 0; mt < 4; mt++)
      afr[mt] = *(const bf16x8*)(&abuf[(wm * 4 + mt) * 512 + lane * 8]);
#pragma unroll
    for (int nt = 0; nt < 4; nt++)
      bfr[nt] = *(const bf16x8*)(&bbuf[(wn * 4 + nt) * 512 + lane * 8]);
    asm volatile("s_waitcnt lgkmcnt(0)" ::: "memory");
    __builtin_amdgcn_sched_barrier(0);
    __builtin_amdgcn_s_setprio(1);
#pragma unroll
    for (int mt = 0; mt < 4; mt++)
#pragma unroll
      for (int nt = 0; nt < 4; nt++)
        acc[mt][nt] = __builtin_amdgcn_mfma_f32_16x16x32_bf16(
            afr[mt], bfr[nt], acc[mt][nt], 0, 0, 0);
    __builtin_amdgcn_s_setprio(0);
  };

  // prologue: stage tiles 0,1,2 (9 loads/wave); vmcnt(6) confirms tile 0
  stage(0); stage(1); stage(2);
  asm volatile("s_waitcnt vmcnt(6)" ::: "memory");
  __builtin_amdgcn_s_barrier();

  for (int t = 0; t < NTK - 3; ++t) {
    stage(t + 3);
    compute(t);
    // counted: leaves {t+2, t+3} = 6 in flight, confirms tile t+1
    asm volatile("s_waitcnt vmcnt(6)" ::: "memory");
    __builtin_amdgcn_s_barrier();
  }
  // tail: 3 staged tiles remain; per-wave vmcnt + barrier (cross-wave stages)
  compute(NTK - 3);
  asm volatile("s_waitcnt vmcnt(3)" ::: "memory");
  __builtin_amdgcn_s_barrier();
  compute(NTK - 2);
  asm volatile("s_waitcnt vmcnt(0)" ::: "memory");
  __builtin_amdgcn_s_barrier();
  compute(NTK - 1);

  // epilogue: row = m0 + wm*64 + mt*16 + quad*4 + r; col = n0 + wn*64 + nt*16 + l15
#pragma unroll
  for (int mt = 0; mt < 4; mt++)
#pragma unroll
    for (int nt = 0; nt < 4; nt++) {
      const int colg = n0 + wn * 64 + nt * 16 + l15;
      const size_t cbase = (size_t)(colg >> 11) * bufStride + (colg & 2047);
#pragma unroll
      for (int r = 0; r < 4; r++) {
        const int row = m0 + wm * 64 + mt * 16 + quad * 4 + r;
        const float v = acc[mt][nt][r];
        if constexpr (sizeof(OutT) == 2)
          C[cbase + (size_t)row * 2048] = f2b(v);
        else
          C[cbase + (size_t)row * 2048] = v;
      }
    }
}

__global__ __launch_bounds__(512, 2) void gemmfo_bf(const u16* __restrict__ A,
                                                    const u16* __restrict__ Bt,
                                                    u16* __restrict__ C,
                                                    int Ntiles, size_t bufStride) {
  gemmfo_core<u16>(A, Bt, C, Ntiles, bufStride);
}
__global__ __launch_bounds__(512, 2) void gemmfo_f32(const u16* __restrict__ A,
                                                     const u16* __restrict__ Bt,
                                                     float* __restrict__ C,
                                                     int Ntiles, size_t bufStride) {
  gemmfo_core<float>(A, Bt, C, Ntiles, bufStride);
}

// ---------------------------------------------------------------------------
// V (B,L,H,Dh) -> Vt (B,H,Dh,L)
// ---------------------------------------------------------------------------
__global__ __launch_bounds__(256) void transpose_v_k(const u16* __restrict__ V,
                                                     u16* __restrict__ Vt) {
  __shared__ __align__(16) u16 tile[64][65];
  const int z = blockIdx.z;
  const int b = z >> 4, h = z & 15;
  const int l0 = blockIdx.y * 64, d0 = blockIdx.x * 64;
  const int tc = threadIdx.x & 63, tr4 = threadIdx.x >> 6;
#pragma unroll
  for (int p = 0; p < 16; p++) {
    int l = tr4 + p * 4;
    tile[l][tc] = V[(size_t)((b * Lc + l0 + l) * Hc + h) * DhC + d0 + tc];
  }
  __syncthreads();
#pragma unroll
  for (int p = 0; p < 16; p++) {
    int dd = tr4 + p * 4;
    Vt[((size_t)z * DhC + d0 + dd) * Lc + l0 + tc] = tile[tc][dd];
  }
}

// ---------------------------------------------------------------------------
// RoPE in place on Q and K; Q additionally scaled by 1/sqrt(Dh).
// ---------------------------------------------------------------------------
__global__ __launch_bounds__(256) void rope_qk(u16* __restrict__ Q, u16* __restrict__ K) {
  const int idx = blockIdx.x * 256 + threadIdx.x;
  const int j = idx & 63;
  const int l = (idx >> 10) & 2047;
  const float inv = expf(-0.2050369278f * (float)j);  // theta^(-j/64)
  const float ang = (float)l * inv;
  float s, c;
  sincosf(ang, &s, &c);
  const size_t off = (size_t)idx * 2;
  const float q0 = b2f(Q[off]), q1 = b2f(Q[off + 1]);
  const float k0 = b2f(K[off]), k1 = b2f(K[off + 1]);
  const float sc = 0.08838834764f;  // 1/sqrt(128)
  Q[off]     = f2b((q0 * c - q1 * s) * sc);
  Q[off + 1] = f2b((q1 * c + q0 * s) * sc);
  K[off]     = f2b(k0 * c - k1 * s);
  K[off + 1] = f2b(k1 * c + k0 * s);
}

// ---------------------------------------------------------------------------
// Flash attention (causal), r7 (unchanged from passing round-1 version).
// ---------------------------------------------------------------------------
#define NEGBIG (-3.0e30f)
__global__ __launch_bounds__(256, 2) void flash_attn(const u16* __restrict__ Q,
                                                     const u16* __restrict__ Kg,
                                                     const u16* __restrict__ Vt,
                                                     u16* __restrict__ O) {
  __shared__ __align__(16) u16 Ks[2][64 * 128];
  __shared__ __align__(16) u16 Vs[2][128 * 64];
  const int tid = threadIdx.x;
  const int lane = tid & 63, w = tid >> 6;
  const int l31 = lane & 31, hib = lane >> 5;
  const int bh = blockIdx.y;
  const int b = bh >> 4, h = bh & 15;
  const int qt = (bh & 16) ? (int)blockIdx.x : (15 - (int)blockIdx.x);
  const int q0 = qt * 128;
  const int qw0 = q0 + w * 32;
  const int nkv = 2 * qt + 2;

  const int krl = lane >> 4, ksl = lane & 15;
  const int vrl = lane >> 3, vsl = lane & 7;

  bf16x8 qf[8];
  {
    const u16* qptr = Q + ((size_t)(b * Lc + qw0 + l31) * Hc + h) * DhC + 8 * hib;
#pragma unroll
    for (int s = 0; s < 8; s++) qf[s] = *(const bf16x8*)(qptr + s * 16);
  }

  {
#pragma unroll
    for (int p = 0; p < 4; p++) {
      const int r = p * 16 + w * 4 + krl;
      const int c = ksl ^ (r & 15);
      gll16(Kg + ((size_t)(b * Lc + r) * Hc + h) * DhC + c * 8,
            &Ks[0][(p * 256 + w * 64) * 8]);
    }
#pragma unroll
    for (int p = 0; p < 4; p++) {
      const int r = p * 32 + w * 8 + vrl;
      const int c = vsl ^ (r & 7);
      gll16(Vt + ((size_t)bh * DhC + r) * Lc + c * 8,
            &Vs[0][(p * 256 + w * 64) * 8]);
    }
  }

  f32x16 o[4];
#pragma unroll
  for (int dt = 0; dt < 4; dt++) o[dt] = (f32x16)0.0f;
  float mrow = NEGBIG, lrow = 0.f;

  __syncthreads();

  for (int kvt = 0; kvt < nkv; kvt++) {
    const int cur = kvt & 1;
    const u16* Ksc = Ks[cur];
    const u16* Vsc = Vs[cur];

    if (kvt + 1 < nkv) {
      const int nv0 = (kvt + 1) * 64;
      const int nxt = cur ^ 1;
#pragma unroll
      for (int p = 0; p < 4; p++) {
        const int r = p * 16 + w * 4 + krl;
        const int c = ksl ^ (r & 15);
        gll16(Kg + ((size_t)(b * Lc + nv0 + r) * Hc + h) * DhC + c * 8,
              &Ks[nxt][(p * 256 + w * 64) * 8]);
      }
#pragma unroll
      for (int p = 0; p < 4; p++) {
        const int r = p * 32 + w * 8 + vrl;
        const int c = vsl ^ (r & 7);
        gll16(Vt + ((size_t)bh * DhC + r) * Lc + nv0 + c * 8,
              &Vs[nxt][(p * 256 + w * 64) * 8]);
      }
    }

    const int kv0 = kvt * 64;
    const bool active = (kv0 <= qw0 + 31);
    if (active) {
      f32x16 s0 = (f32x16)0.0f, s1 = (f32x16)0.0f;
      __builtin_amdgcn_s_setprio(1);
#pragma unroll
      for (int s = 0; s < 8; s++) {
        const int ch = ((2 * s + hib) ^ (l31 & 15)) * 8;
        bf16x8 k0 = *(const bf16x8*)(&Ksc[l31 * 128 + ch]);
        bf16x8 k1 = *(const bf16x8*)(&Ksc[(32 + l31) * 128 + ch]);
        s0 = __builtin_amdgcn_mfma_f32_32x32x16_bf16(k0, qf[s], s0, 0, 0, 0);
        s1 = __builtin_amdgcn_mfma_f32_32x32x16_bf16(k1, qf[s], s1, 0, 0, 0);
      }
      __builtin_amdgcn_s_setprio(0);

      if (kv0 + 63 > qw0) {
        const int qg = qw0 + l31;
#pragma unroll
        for (int r = 0; r < 16; r++) {
          const int cr = (r & 3) + 8 * (r >> 2) + 4 * hib;
          if (kv0 + cr > qg) s0[r] = NEGBIG;
          if (kv0 + 32 + cr > qg) s1[r] = NEGBIG;
        }
      }

      float mx;
      {
        float a[8];
#pragma unroll
        for (int i = 0; i < 8; i++)
          a[i] = fmaxf(fmaxf(s0[i], s0[i + 8]), fmaxf(s1[i], s1[i + 8]));
        float b0 = fmaxf(a[0], a[4]), b1 = fmaxf(a[1], a[5]);
        float b2 = fmaxf(a[2], a[6]), b3 = fmaxf(a[3], a[7]);
        mx = fmaxf(fmaxf(b0, b1), fmaxf(b2, b3));
      }
      mx = fmaxf(mx, __shfl_xor(mx, 32, 64));

      if (!__all(mx - mrow <= 8.f)) {
        const float mnew = fmaxf(mrow, mx);
        const float al = __expf(mrow - mnew);
#pragma unroll
        for (int dt = 0; dt < 4; dt++)
#pragma unroll
          for (int e = 0; e < 16; e++) o[dt][e] *= al;
        lrow *= al;
        mrow = mnew;
      }

#pragma unroll
      for (int i = 0; i < 16; i++) {
        s0[i] = __expf(s0[i] - mrow);
        s1[i] = __expf(s1[i] - mrow);
      }
      float sm;
      {
        float a[8];
#pragma unroll
        for (int i = 0; i < 8; i++)
          a[i] = (s0[i] + s0[i + 8]) + (s1[i] + s1[i + 8]);
        sm = ((a[0] + a[4]) + (a[1] + a[5])) + ((a[2] + a[6]) + (a[3] + a[7]));
      }
      sm += __shfl_xor(sm, 32, 64);
      lrow += sm;

      bf16x8 paf[4];
#pragma unroll
      for (int t = 0; t < 2; t++) {
#pragma unroll
        for (int h8 = 0; h8 < 2; h8++) {
          const int rB = 8 * h8;
          u32 lo0, lo1, hi0, hi1;
          if (t == 0) {
            lo0 = cvtpk(s0[rB + 0], s0[rB + 1]);
            lo1 = cvtpk(s0[rB + 2], s0[rB + 3]);
            hi0 = cvtpk(s0[rB + 4], s0[rB + 5]);
            hi1 = cvtpk(s0[rB + 6], s0[rB + 7]);
          } else {
            lo0 = cvtpk(s1[rB + 0], s1[rB + 1]);
            lo1 = cvtpk(s1[rB + 2], s1[rB + 3]);
            hi0 = cvtpk(s1[rB + 4], s1[rB + 5]);
            hi1 = cvtpk(s1[rB + 6], s1[rB + 7]);
          }
          const u32 g0 = hib ? lo0 : hi0;
          const u32 g1 = hib ? lo1 : hi1;
          const u32 r0 = (u32)__shfl_xor((int)g0, 32, 64);
          const u32 r1 = (u32)__shfl_xor((int)g1, 32, 64);
          union { u32 u[4]; bf16x8 v; } pu;
          pu.u[0] = hib ? r0 : lo0;
          pu.u[1] = hib ? r1 : lo1;
          pu.u[2] = hib ? hi0 : r0;
          pu.u[3] = hib ? hi1 : r1;
          paf[2 * t + h8] = pu.v;
        }
      }

      __builtin_amdgcn_s_setprio(1);
#pragma unroll
      for (int B = 0; B < 4; B++) {
#pragma unroll
        for (int dt = 0; dt < 4; dt++) {
          const bf16x8 vf = *(const bf16x8*)(
              &Vsc[(32 * dt + l31) * 64 + (((2 * B + hib) ^ (l31 & 7))) * 8]);
          o[dt] = __builtin_amdgcn_mfma_f32_32x32x16_bf16(paf[B], vf, o[dt], 0, 0, 0);
        }
      }
      __builtin_amdgcn_s_setprio(0);
    }

    __syncthreads();
  }

#pragma unroll
  for (int r = 0; r < 16; r++) {
    const int cr = (r & 3) + 8 * (r >> 2) + 4 * hib;
    const float linv = 1.0f / __shfl(lrow, cr, 64);
    const size_t rowoff = ((size_t)(b * Lc + qw0 + cr) * Hc + h) * DhC + l31;
#pragma unroll
    for (int dt = 0; dt < 4; dt++)
      O[rowoff + 32 * dt] = f2b(o[dt][r] * linv);
  }
}

// ---------------------------------------------------------------------------
// ws layout (72 MiB + 256 B peak), serial weight-slot reuse:
//   [0,256) flag | WT 8MiB (Wo only) | xc 16MiB | Qb 16MiB | Kb 16MiB | Vb 16MiB
//   Qb,Kb,Vb contiguous (fused-QKV gemm writes via (col>>11)*XSZ).
//   WTall (24MiB, 3 transposed QKV weights) lives in d_out-as-scratch
//   (32MiB, fully overwritten by the final gemm). Vtb aliases xc; Ob aliases Vb.
// ---------------------------------------------------------------------------
extern "C" void kernel_launch(void* const* d_in, const int* in_sizes, int n_in,
                              void* d_out, int out_size, void* d_ws, size_t ws_size,
                              hipStream_t stream) {
  const void* x  = d_in[0];
  const void* Wq = d_in[1];
  const void* Wk = d_in[2];
  const void* Wv = d_in[3];
  const void* Wo = d_in[4];
  float* out = (float*)d_out;   // reference output dtype: float32 (verified r4)

  char* w = (char*)d_ws;
  const size_t WSZ = (size_t)2048 * 2048;
  const size_t XSZ = (size_t)Bb * Lc * Dc;
  int* flag = (int*)w;
  u16* WT  = (u16*)(w + 256);
  u16* xc  = WT + WSZ;
  u16* Qb  = xc + XSZ;
  u16* Kb  = Qb + XSZ;
  u16* Vb  = Kb + XSZ;
  u16* Vtb = xc;
  u16* Ob  = Vb;
  u16* WTall = (u16*)d_out;   // 24 MiB scratch inside the 32 MiB output

  sniff_dtype<<<1, 256, 0, stream>>>((const u16*)x, flag);
  conv_x<<<(int)(XSZ / 1024), 256, 0, stream>>>(x, xc, flag);

  dim3 tgrid(32, 32);

  transpose2d_conv<<<tgrid, 256, 0, stream>>>(Wq, WTall, flag);
  transpose2d_conv<<<tgrid, 256, 0, stream>>>(Wk, WTall + WSZ, flag);
  transpose2d_conv<<<tgrid, 256, 0, stream>>>(Wv, WTall + 2 * WSZ, flag);

  // fused QKV: C[4096, 6144] = xc @ [Wq|Wk|Wv]^T -> Qb/Kb/Vb via col>>11
  gemmfo_bf<<<dim3(768), 512, 0, stream>>>(xc, WTall, Qb, 24, XSZ);

  rope_qk<<<(Bb * Lc * Hc * 64) / 256, 256, 0, stream>>>(Qb, Kb);

  dim3 vgrid(2, 32, 32);
  transpose_v_k<<<vgrid, 256, 0, stream>>>(Vb, Vtb);

  dim3 fgrid(16, 32);
  flash_attn<<<fgrid, 256, 0, stream>>>(Qb, Kb, Vtb, Ob);

  transpose2d_conv<<<tgrid, 256, 0, stream>>>(Wo, WT, flag);
  gemmfo_f32<<<dim3(256), 512, 0, stream>>>(Ob, WT, out, 8, 0);
}

// Round 5
// 572.056 us; speedup vs baseline: 1.0738x; 1.0738x over previous
//
#include <hip/hip_runtime.h>

typedef unsigned short u16;
typedef unsigned int u32;

#define Bb 2
#define Lc 2048
#define Dc 2048
#define Hc 16
#define DhC 128

typedef __bf16 bf16x8 __attribute__((ext_vector_type(8)));
typedef float f32x4 __attribute__((ext_vector_type(4)));
typedef float f32x16 __attribute__((ext_vector_type(16)));

__device__ __forceinline__ u16 f2b(float f) {
  u32 u = __float_as_uint(f);
  u32 r = (u + 0x7fffu + ((u >> 16) & 1u)) >> 16;
  return (u16)r;
}
__device__ __forceinline__ float b2f(u16 u) {
  return __uint_as_float(((u32)u) << 16);
}

// pack 2 f32 -> 1 u32 of 2 bf16 (lo in low half) -- T12 recipe, no builtin
__device__ __forceinline__ u32 cvtpk(float lo, float hi) {
  u32 r;
  asm("v_cvt_pk_bf16_f32 %0, %1, %2" : "=v"(r) : "v"(lo), "v"(hi));
  return r;
}

// async global->LDS DMA, 16B/lane; LDS dest = wave-uniform base + lane*16
__device__ __forceinline__ void gll16(const void* g, void* l) {
  __builtin_amdgcn_global_load_lds(
      (const __attribute__((address_space(1))) u32*)g,
      (__attribute__((address_space(3))) u32*)l, 16, 0, 0);
}

// ---------------------------------------------------------------------------
// Dtype sniffer + x canonicalize (kept; inputs verified bf16-compatible r4).
// ---------------------------------------------------------------------------
__global__ __launch_bounds__(256) void sniff_dtype(const u16* __restrict__ x,
                                                   int* __restrict__ flag) {
  __shared__ int bad;
  if (threadIdx.x == 0) bad = 0;
  __syncthreads();
  int local = 0;
  for (int i = threadIdx.x; i < 65536; i += 256) {
    float v = fabsf(b2f(x[i]));
    if (!(v < 1000.f)) local = 1;
  }
  if (local) atomicOr(&bad, 1);
  __syncthreads();
  if (threadIdx.x == 0) *flag = bad;
}

__global__ __launch_bounds__(256) void conv_x(const void* __restrict__ in,
                                              u16* __restrict__ out,
                                              const int* __restrict__ flag) {
  const int f32 = *flag;
  const int i0 = (blockIdx.x * 256 + threadIdx.x) * 4;
  if (f32) {
    const float* p = (const float*)in;
#pragma unroll
    for (int j = 0; j < 4; j++) out[i0 + j] = f2b(p[i0 + j]);
  } else {
    const u16* p = (const u16*)in;
#pragma unroll
    for (int j = 0; j < 4; j++) out[i0 + j] = p[i0 + j];
  }
}

// ---------------------------------------------------------------------------
// 2048x2048 transpose with dtype conversion (weights -> bf16 W^T).
// transpose3_conv: z-indexed fused variant for the 3 QKV weights.
// ---------------------------------------------------------------------------
__device__ __forceinline__ void tconv_body(const void* in, u16* out, int f32) {
  __shared__ __align__(16) u16 tile[64][65];
  const int r0 = blockIdx.y * 64, c0 = blockIdx.x * 64;
  const int tc = threadIdx.x & 63, tr4 = threadIdx.x >> 6;
#pragma unroll
  for (int p = 0; p < 16; p++) {
    int r = tr4 + p * 4;
    size_t idx = (size_t)(r0 + r) * 2048 + c0 + tc;
    tile[r][tc] = f32 ? f2b(((const float*)in)[idx]) : ((const u16*)in)[idx];
  }
  __syncthreads();
#pragma unroll
  for (int p = 0; p < 16; p++) {
    int rr = tr4 + p * 4;
    out[(size_t)(c0 + rr) * 2048 + r0 + tc] = tile[tc][rr];
  }
}

__global__ __launch_bounds__(256) void transpose2d_conv(const void* __restrict__ in,
                                                        u16* __restrict__ out,
                                                        const int* __restrict__ flag) {
  tconv_body(in, out, *flag);
}

__global__ __launch_bounds__(256) void transpose3_conv(const void* __restrict__ W0,
                                                       const void* __restrict__ W1,
                                                       const void* __restrict__ W2,
                                                       u16* __restrict__ out,
                                                       const int* __restrict__ flag) {
  const int z = blockIdx.z;
  const void* in = (z == 0) ? W0 : (z == 1) ? W1 : W2;
  tconv_body(in, out + (size_t)z * 2048 * 2048, *flag);
}

// ---------------------------------------------------------------------------
// GEMM r11 "gemmp": 128x128 tile, BK=32, 256 thr (4 waves 2x2, per-wave
// 64x64 = acc[4][4]), FRAGMENT-ORDER LDS (0 conflicts, verified r10),
// 3-slot ring (48 KB -> 3 blocks/CU = 12 waves/CU: restores gemm_bt's TLP,
// the thing r9/r10's 1-block/CU kernels lost) + counted vmcnt (never 0 in
// main loop) + XCD-chunked swizzle. Grids are exact multiples of 256:
// QKV 1536 (6 rounds), Wo 512 (2 rounds).
//  - fragment-order: subtile s (16 rows x 32 cols, 1 KB) stored so read-lane
//    l's fragment (row l&15, k-chunk l>>4) sits at subtile_base + l*16B.
//    Staging gll16 src = per-lane global (row l&15, chunk l>>4); dest linear.
//  - ring distance 2: iter t computes slot t%3, stages tile t+2 into slot
//    (t+2)%3 (== slot read in iter t-1, freed by its end barrier).
//    4 gll16/thread/tile -> vmcnt(4) at iter end confirms tile t+1.
//  - C col: (col>>11) selects output buffer (stride bufStride) for fused QKV.
// ---------------------------------------------------------------------------
template <typename OutT>
__device__ __forceinline__ void gemmp_core(const u16* __restrict__ A,
                                           const u16* __restrict__ Bt,
                                           OutT* __restrict__ C,
                                           int Ntiles, size_t bufStride) {
  constexpr int K = 2048;
  constexpr int NTK = K / 32;  // 64 K-tiles
  __shared__ __align__(16) u16 Als[3][128 * 32];
  __shared__ __align__(16) u16 Bls[3][128 * 32];

  const int tid = threadIdx.x;
  const int lane = tid & 63, w = tid >> 6;  // 4 waves
  const int quad = lane >> 4, l15 = lane & 15;
  const int wm = w >> 1, wn = w & 1;  // 2M x 2N waves, per-wave 64x64

  // XCD-chunked bijective swizzle (nwg % 8 == 0: 1536 and 512)
  const int nwg = 32 * Ntiles;  // Mtiles = 32 (M = 4096)
  const int q8 = nwg >> 3;
  const int id = (int)blockIdx.x;
  const int swz = (id & 7) * q8 + (id >> 3);
  const int m0 = (swz & 31) * 128;
  const int n0 = (swz >> 5) * 128;

  // fragment-order staging: wave w stages subtiles {2w, 2w+1} of A and B
  const u16* aSrc0 = A + (size_t)(m0 + (2 * w) * 16 + l15) * K + quad * 8;
  const u16* aSrc1 = A + (size_t)(m0 + (2 * w + 1) * 16 + l15) * K + quad * 8;
  const u16* bSrc0 = Bt + (size_t)(n0 + (2 * w) * 16 + l15) * K + quad * 8;
  const u16* bSrc1 = Bt + (size_t)(n0 + (2 * w + 1) * 16 + l15) * K + quad * 8;

  const f32x4 fz = {0.f, 0.f, 0.f, 0.f};
  f32x4 acc[4][4];
#pragma unroll
  for (int i = 0; i < 4; i++)
#pragma unroll
    for (int j = 0; j < 4; j++) acc[i][j] = fz;

  auto stage = [&](int t) {
    const int s = t % 3;
    const int k = t * 32;
    gll16(aSrc0 + k, &Als[s][(2 * w) * 512]);
    gll16(aSrc1 + k, &Als[s][(2 * w + 1) * 512]);
    gll16(bSrc0 + k, &Bls[s][(2 * w) * 512]);
    gll16(bSrc1 + k, &Bls[s][(2 * w + 1) * 512]);
  };

  auto compute = [&](int t) {
    const int s = t % 3;
    bf16x8 afr[4], bfr[4];
#pragma unroll
    for (int mt = 0; mt < 4; mt++)
      afr[mt] = *(const bf16x8*)(&Als[s][(wm * 4 + mt) * 512 + lane * 8]);
#pragma unroll
    for (int nt = 0; nt < 4; nt++)
      bfr[nt] = *(const bf16x8*)(&Bls[s][(wn * 4 + nt) * 512 + lane * 8]);
    asm volatile("s_waitcnt lgkmcnt(0)" ::: "memory");
    __builtin_amdgcn_sched_barrier(0);
    __builtin_amdgcn_s_setprio(1);
#pragma unroll
    for (int mt = 0; mt < 4; mt++)
#pragma unroll
      for (int nt = 0; nt < 4; nt++)
        acc[mt][nt] = __builtin_amdgcn_mfma_f32_16x16x32_bf16(
            afr[mt], bfr[nt], acc[mt][nt], 0, 0, 0);
    __builtin_amdgcn_s_setprio(0);
  };

  // prologue: stage tiles 0,1 (8 issues/thread); vmcnt(4) confirms tile 0
  stage(0);
  stage(1);
  asm volatile("s_waitcnt vmcnt(4)" ::: "memory");
  __builtin_amdgcn_s_barrier();

  for (int t = 0; t < NTK - 2; ++t) {
    stage(t + 2);            // -> outstanding: t+1 (4), t+2 (4)
    compute(t);
    asm volatile("s_waitcnt vmcnt(4)" ::: "memory");  // confirms t+1
    __builtin_amdgcn_s_barrier();
  }
  // tail: tiles NTK-2 (confirmed), NTK-1 (in flight)
  compute(NTK - 2);
  asm volatile("s_waitcnt vmcnt(0)" ::: "memory");
  __builtin_amdgcn_s_barrier();
  compute(NTK - 1);

  // epilogue: row = m0 + wm*64 + mt*16 + quad*4 + r; col = n0 + wn*64 + nt*16 + l15
#pragma unroll
  for (int mt = 0; mt < 4; mt++)
#pragma unroll
    for (int nt = 0; nt < 4; nt++) {
      const int colg = n0 + wn * 64 + nt * 16 + l15;
      const size_t cbase = (size_t)(colg >> 11) * bufStride + (colg & 2047);
#pragma unroll
      for (int r = 0; r < 4; r++) {
        const int row = m0 + wm * 64 + mt * 16 + quad * 4 + r;
        const float v = acc[mt][nt][r];
        if constexpr (sizeof(OutT) == 2)
          C[cbase + (size_t)row * 2048] = f2b(v);
        else
          C[cbase + (size_t)row * 2048] = v;
      }
    }
}

__global__ __launch_bounds__(256, 4) void gemmp_bf(const u16* __restrict__ A,
                                                   const u16* __restrict__ Bt,
                                                   u16* __restrict__ C,
                                                   int Ntiles, size_t bufStride) {
  gemmp_core<u16>(A, Bt, C, Ntiles, bufStride);
}
__global__ __launch_bounds__(256, 4) void gemmp_f32(const u16* __restrict__ A,
                                                    const u16* __restrict__ Bt,
                                                    float* __restrict__ C,
                                                    int Ntiles, size_t bufStride) {
  gemmp_core<float>(A, Bt, C, Ntiles, bufStride);
}

// ---------------------------------------------------------------------------
// V (B,L,H,Dh) -> Vt (B,H,Dh,L)
// ---------------------------------------------------------------------------
__global__ __launch_bounds__(256) void transpose_v_k(const u16* __restrict__ V,
                                                     u16* __restrict__ Vt) {
  __shared__ __align__(16) u16 tile[64][65];
  const int z = blockIdx.z;
  const int b = z >> 4, h = z & 15;
  const int l0 = blockIdx.y * 64, d0 = blockIdx.x * 64;
  const int tc = threadIdx.x & 63, tr4 = threadIdx.x >> 6;
#pragma unroll
  for (int p = 0; p < 16; p++) {
    int l = tr4 + p * 4;
    tile[l][tc] = V[(size_t)((b * Lc + l0 + l) * Hc + h) * DhC + d0 + tc];
  }
  __syncthreads();
#pragma unroll
  for (int p = 0; p < 16; p++) {
    int dd = tr4 + p * 4;
    Vt[((size_t)z * DhC + d0 + dd) * Lc + l0 + tc] = tile[tc][dd];
  }
}

// ---------------------------------------------------------------------------
// RoPE in place on Q and K; Q additionally scaled by 1/sqrt(Dh).
// r11: one thread per (l,h,j), batch loop inside -> transcendentals halved;
// exp2f (native v_exp_f32) instead of expf.
// ---------------------------------------------------------------------------
__global__ __launch_bounds__(256) void rope_qk(u16* __restrict__ Q, u16* __restrict__ K) {
  const int idx = blockIdx.x * 256 + threadIdx.x;  // (l, h, j)
  const int j = idx & 63;
  const int h = (idx >> 6) & 15;
  const int l = idx >> 10;
  const float inv = exp2f(-0.2958057561f * (float)j);  // theta^(-j/64)
  const float ang = (float)l * inv;
  float s, c;
  sincosf(ang, &s, &c);
  const float sc = 0.08838834764f;  // 1/sqrt(128)
#pragma unroll
  for (int b = 0; b < Bb; b++) {
    const size_t off = ((size_t)((b * Lc + l) * Hc + h)) * DhC + 2 * j;
    const float q0 = b2f(Q[off]), q1 = b2f(Q[off + 1]);
    const float k0 = b2f(K[off]), k1 = b2f(K[off + 1]);
    Q[off]     = f2b((q0 * c - q1 * s) * sc);
    Q[off + 1] = f2b((q1 * c + q0 * s) * sc);
    K[off]     = f2b(k0 * c - k1 * s);
    K[off + 1] = f2b(k1 * c + k0 * s);
  }
}

// ---------------------------------------------------------------------------
// Flash attention (causal), unchanged from passing round-1 version.
// ---------------------------------------------------------------------------
#define NEGBIG (-3.0e30f)
__global__ __launch_bounds__(256, 2) void flash_attn(const u16* __restrict__ Q,
                                                     const u16* __restrict__ Kg,
                                                     const u16* __restrict__ Vt,
                                                     u16* __restrict__ O) {
  __shared__ __align__(16) u16 Ks[2][64 * 128];
  __shared__ __align__(16) u16 Vs[2][128 * 64];
  const int tid = threadIdx.x;
  const int lane = tid & 63, w = tid >> 6;
  const int l31 = lane & 31, hib = lane >> 5;
  const int bh = blockIdx.y;
  const int b = bh >> 4, h = bh & 15;
  const int qt = (bh & 16) ? (int)blockIdx.x : (15 - (int)blockIdx.x);
  const int q0 = qt * 128;
  const int qw0 = q0 + w * 32;
  const int nkv = 2 * qt + 2;

  const int krl = lane >> 4, ksl = lane & 15;
  const int vrl = lane >> 3, vsl = lane & 7;

  bf16x8 qf[8];
  {
    const u16* qptr = Q + ((size_t)(b * Lc + qw0 + l31) * Hc + h) * DhC + 8 * hib;
#pragma unroll
    for (int s = 0; s < 8; s++) qf[s] = *(const bf16x8*)(qptr + s * 16);
  }

  {
#pragma unroll
    for (int p = 0; p < 4; p++) {
      const int r = p * 16 + w * 4 + krl;
      const int c = ksl ^ (r & 15);
      gll16(Kg + ((size_t)(b * Lc + r) * Hc + h) * DhC + c * 8,
            &Ks[0][(p * 256 + w * 64) * 8]);
    }
#pragma unroll
    for (int p = 0; p < 4; p++) {
      const int r = p * 32 + w * 8 + vrl;
      const int c = vsl ^ (r & 7);
      gll16(Vt + ((size_t)bh * DhC + r) * Lc + c * 8,
            &Vs[0][(p * 256 + w * 64) * 8]);
    }
  }

  f32x16 o[4];
#pragma unroll
  for (int dt = 0; dt < 4; dt++) o[dt] = (f32x16)0.0f;
  float mrow = NEGBIG, lrow = 0.f;

  __syncthreads();

  for (int kvt = 0; kvt < nkv; kvt++) {
    const int cur = kvt & 1;
    const u16* Ksc = Ks[cur];
    const u16* Vsc = Vs[cur];

    if (kvt + 1 < nkv) {
      const int nv0 = (kvt + 1) * 64;
      const int nxt = cur ^ 1;
#pragma unroll
      for (int p = 0; p < 4; p++) {
        const int r = p * 16 + w * 4 + krl;
        const int c = ksl ^ (r & 15);
        gll16(Kg + ((size_t)(b * Lc + nv0 + r) * Hc + h) * DhC + c * 8,
              &Ks[nxt][(p * 256 + w * 64) * 8]);
      }
#pragma unroll
      for (int p = 0; p < 4; p++) {
        const int r = p * 32 + w * 8 + vrl;
        const int c = vsl ^ (r & 7);
        gll16(Vt + ((size_t)bh * DhC + r) * Lc + nv0 + c * 8,
              &Vs[nxt][(p * 256 + w * 64) * 8]);
      }
    }

    const int kv0 = kvt * 64;
    const bool active = (kv0 <= qw0 + 31);
    if (active) {
      f32x16 s0 = (f32x16)0.0f, s1 = (f32x16)0.0f;
      __builtin_amdgcn_s_setprio(1);
#pragma unroll
      for (int s = 0; s < 8; s++) {
        const int ch = ((2 * s + hib) ^ (l31 & 15)) * 8;
        bf16x8 k0 = *(const bf16x8*)(&Ksc[l31 * 128 + ch]);
        bf16x8 k1 = *(const bf16x8*)(&Ksc[(32 + l31) * 128 + ch]);
        s0 = __builtin_amdgcn_mfma_f32_32x32x16_bf16(k0, qf[s], s0, 0, 0, 0);
        s1 = __builtin_amdgcn_mfma_f32_32x32x16_bf16(k1, qf[s], s1, 0, 0, 0);
      }
      __builtin_amdgcn_s_setprio(0);

      if (kv0 + 63 > qw0) {
        const int qg = qw0 + l31;
#pragma unroll
        for (int r = 0; r < 16; r++) {
          const int cr = (r & 3) + 8 * (r >> 2) + 4 * hib;
          if (kv0 + cr > qg) s0[r] = NEGBIG;
          if (kv0 + 32 + cr > qg) s1[r] = NEGBIG;
        }
      }

      float mx;
      {
        float a[8];
#pragma unroll
        for (int i = 0; i < 8; i++)
          a[i] = fmaxf(fmaxf(s0[i], s0[i + 8]), fmaxf(s1[i], s1[i + 8]));
        float b0 = fmaxf(a[0], a[4]), b1 = fmaxf(a[1], a[5]);
        float b2 = fmaxf(a[2], a[6]), b3 = fmaxf(a[3], a[7]);
        mx = fmaxf(fmaxf(b0, b1), fmaxf(b2, b3));
      }
      mx = fmaxf(mx, __shfl_xor(mx, 32, 64));

      if (!__all(mx - mrow <= 8.f)) {
        const float mnew = fmaxf(mrow, mx);
        const float al = __expf(mrow - mnew);
#pragma unroll
        for (int dt = 0; dt < 4; dt++)
#pragma unroll
          for (int e = 0; e < 16; e++) o[dt][e] *= al;
        lrow *= al;
        mrow = mnew;
      }

#pragma unroll
      for (int i = 0; i < 16; i++) {
        s0[i] = __expf(s0[i] - mrow);
        s1[i] = __expf(s1[i] - mrow);
      }
      float sm;
      {
        float a[8];
#pragma unroll
        for (int i = 0; i < 8; i++)
          a[i] = (s0[i] + s0[i + 8]) + (s1[i] + s1[i + 8]);
        sm = ((a[0] + a[4]) + (a[1] + a[5])) + ((a[2] + a[6]) + (a[3] + a[7]));
      }
      sm += __shfl_xor(sm, 32, 64);
      lrow += sm;

      bf16x8 paf[4];
#pragma unroll
      for (int t = 0; t < 2; t++) {
#pragma unroll
        for (int h8 = 0; h8 < 2; h8++) {
          const int rB = 8 * h8;
          u32 lo0, lo1, hi0, hi1;
          if (t == 0) {
            lo0 = cvtpk(s0[rB + 0], s0[rB + 1]);
            lo1 = cvtpk(s0[rB + 2], s0[rB + 3]);
            hi0 = cvtpk(s0[rB + 4], s0[rB + 5]);
            hi1 = cvtpk(s0[rB + 6], s0[rB + 7]);
          } else {
            lo0 = cvtpk(s1[rB + 0], s1[rB + 1]);
            lo1 = cvtpk(s1[rB + 2], s1[rB + 3]);
            hi0 = cvtpk(s1[rB + 4], s1[rB + 5]);
            hi1 = cvtpk(s1[rB + 6], s1[rB + 7]);
          }
          const u32 g0 = hib ? lo0 : hi0;
          const u32 g1 = hib ? lo1 : hi1;
          const u32 r0 = (u32)__shfl_xor((int)g0, 32, 64);
          const u32 r1 = (u32)__shfl_xor((int)g1, 32, 64);
          union { u32 u[4]; bf16x8 v; } pu;
          pu.u[0] = hib ? r0 : lo0;
          pu.u[1] = hib ? r1 : lo1;
          pu.u[2] = hib ? hi0 : r0;
          pu.u[3] = hib ? hi1 : r1;
          paf[2 * t + h8] = pu.v;
        }
      }

      __builtin_amdgcn_s_setprio(1);
#pragma unroll
      for (int B = 0; B < 4; B++) {
#pragma unroll
        for (int dt = 0; dt < 4; dt++) {
          const bf16x8 vf = *(const bf16x8*)(
              &Vsc[(32 * dt + l31) * 64 + (((2 * B + hib) ^ (l31 & 7))) * 8]);
          o[dt] = __builtin_amdgcn_mfma_f32_32x32x16_bf16(paf[B], vf, o[dt], 0, 0, 0);
        }
      }
      __builtin_amdgcn_s_setprio(0);
    }

    __syncthreads();
  }

#pragma unroll
  for (int r = 0; r < 16; r++) {
    const int cr = (r & 3) + 8 * (r >> 2) + 4 * hib;
    const float linv = 1.0f / __shfl(lrow, cr, 64);
    const size_t rowoff = ((size_t)(b * Lc + qw0 + cr) * Hc + h) * DhC + l31;
#pragma unroll
    for (int dt = 0; dt < 4; dt++)
      O[rowoff + 32 * dt] = f2b(o[dt][r] * linv);
  }
}

// ---------------------------------------------------------------------------
// ws layout (72 MiB + 256 B peak), serial weight-slot reuse:
//   [0,256) flag | WT 8MiB (Wo only) | xc 16MiB | Qb 16MiB | Kb 16MiB | Vb 16MiB
//   Qb,Kb,Vb contiguous (fused-QKV gemm writes via (col>>11)*XSZ).
//   WTall (24MiB, 3 transposed QKV weights) lives in d_out-as-scratch
//   (32MiB, fully overwritten by the final gemm). Vtb aliases xc; Ob aliases Vb.
// ---------------------------------------------------------------------------
extern "C" void kernel_launch(void* const* d_in, const int* in_sizes, int n_in,
                              void* d_out, int out_size, void* d_ws, size_t ws_size,
                              hipStream_t stream) {
  const void* x  = d_in[0];
  const void* Wq = d_in[1];
  const void* Wk = d_in[2];
  const void* Wv = d_in[3];
  const void* Wo = d_in[4];
  float* out = (float*)d_out;   // reference output dtype: float32 (verified r4)

  char* w = (char*)d_ws;
  const size_t WSZ = (size_t)2048 * 2048;
  const size_t XSZ = (size_t)Bb * Lc * Dc;
  int* flag = (int*)w;
  u16* WT  = (u16*)(w + 256);
  u16* xc  = WT + WSZ;
  u16* Qb  = xc + XSZ;
  u16* Kb  = Qb + XSZ;
  u16* Vb  = Kb + XSZ;
  u16* Vtb = xc;
  u16* Ob  = Vb;
  u16* WTall = (u16*)d_out;   // 24 MiB scratch inside the 32 MiB output

  sniff_dtype<<<1, 256, 0, stream>>>((const u16*)x, flag);
  conv_x<<<(int)(XSZ / 1024), 256, 0, stream>>>(x, xc, flag);

  // all three QKV weight transposes in one dispatch
  transpose3_conv<<<dim3(32, 32, 3), 256, 0, stream>>>(Wq, Wk, Wv, WTall, flag);

  // fused QKV: C[4096, 6144] = xc @ [Wq|Wk|Wv]^T -> Qb/Kb/Vb via col>>11
  gemmp_bf<<<dim3(1536), 256, 0, stream>>>(xc, WTall, Qb, 48, XSZ);

  rope_qk<<<(Lc * Hc * 64) / 256, 256, 0, stream>>>(Qb, Kb);

  dim3 vgrid(2, 32, 32);
  transpose_v_k<<<vgrid, 256, 0, stream>>>(Vb, Vtb);

  dim3 fgrid(16, 32);
  flash_attn<<<fgrid, 256, 0, stream>>>(Qb, Kb, Vtb, Ob);

  dim3 tgrid(32, 32);
  transpose2d_conv<<<tgrid, 256, 0, stream>>>(Wo, WT, flag);
  gemmp_f32<<<dim3(512), 256, 0, stream>>>(Ob, WT, out, 16, 0);
}

// Round 6
// 531.058 us; speedup vs baseline: 1.1567x; 1.0772x over previous
//
#include <hip/hip_runtime.h>

typedef unsigned short u16;
typedef unsigned int u32;

#define Bb 2
#define Lc 2048
#define Dc 2048
#define Hc 16
#define DhC 128

typedef __bf16 bf16x8 __attribute__((ext_vector_type(8)));
typedef float f32x4 __attribute__((ext_vector_type(4)));
typedef float f32x16 __attribute__((ext_vector_type(16)));

__device__ __forceinline__ u16 f2b(float f) {
  u32 u = __float_as_uint(f);
  u32 r = (u + 0x7fffu + ((u >> 16) & 1u)) >> 16;
  return (u16)r;
}
__device__ __forceinline__ float b2f(u16 u) {
  return __uint_as_float(((u32)u) << 16);
}

// pack 2 f32 -> 1 u32 of 2 bf16 (lo in low half) -- T12 recipe, no builtin
__device__ __forceinline__ u32 cvtpk(float lo, float hi) {
  u32 r;
  asm("v_cvt_pk_bf16_f32 %0, %1, %2" : "=v"(r) : "v"(lo), "v"(hi));
  return r;
}

// async global->LDS DMA, 16B/lane; LDS dest = wave-uniform base + lane*16
__device__ __forceinline__ void gll16(const void* g, void* l) {
  __builtin_amdgcn_global_load_lds(
      (const __attribute__((address_space(1))) u32*)g,
      (__attribute__((address_space(3))) u32*)l, 16, 0, 0);
}

// ---------------------------------------------------------------------------
// Dtype sniffer + x canonicalize (kept; inputs verified bf16-compatible r4).
// ---------------------------------------------------------------------------
__global__ __launch_bounds__(256) void sniff_dtype(const u16* __restrict__ x,
                                                   int* __restrict__ flag) {
  __shared__ int bad;
  if (threadIdx.x == 0) bad = 0;
  __syncthreads();
  int local = 0;
  for (int i = threadIdx.x; i < 65536; i += 256) {
    float v = fabsf(b2f(x[i]));
    if (!(v < 1000.f)) local = 1;
  }
  if (local) atomicOr(&bad, 1);
  __syncthreads();
  if (threadIdx.x == 0) *flag = bad;
}

__global__ __launch_bounds__(256) void conv_x(const void* __restrict__ in,
                                              u16* __restrict__ out,
                                              const int* __restrict__ flag) {
  const int f32 = *flag;
  const int i0 = (blockIdx.x * 256 + threadIdx.x) * 4;
  if (f32) {
    const float* p = (const float*)in;
#pragma unroll
    for (int j = 0; j < 4; j++) out[i0 + j] = f2b(p[i0 + j]);
  } else {
    const u16* p = (const u16*)in;
#pragma unroll
    for (int j = 0; j < 4; j++) out[i0 + j] = p[i0 + j];
  }
}

// ---------------------------------------------------------------------------
// 2048x2048 transpose with dtype conversion (weights -> bf16 W^T).
// transpose3_conv: z-indexed fused variant for the 3 QKV weights.
// ---------------------------------------------------------------------------
__device__ __forceinline__ void tconv_body(const void* in, u16* out, int f32) {
  __shared__ __align__(16) u16 tile[64][65];
  const int r0 = blockIdx.y * 64, c0 = blockIdx.x * 64;
  const int tc = threadIdx.x & 63, tr4 = threadIdx.x >> 6;
#pragma unroll
  for (int p = 0; p < 16; p++) {
    int r = tr4 + p * 4;
    size_t idx = (size_t)(r0 + r) * 2048 + c0 + tc;
    tile[r][tc] = f32 ? f2b(((const float*)in)[idx]) : ((const u16*)in)[idx];
  }
  __syncthreads();
#pragma unroll
  for (int p = 0; p < 16; p++) {
    int rr = tr4 + p * 4;
    out[(size_t)(c0 + rr) * 2048 + r0 + tc] = tile[tc][rr];
  }
}

__global__ __launch_bounds__(256) void transpose2d_conv(const void* __restrict__ in,
                                                        u16* __restrict__ out,
                                                        const int* __restrict__ flag) {
  tconv_body(in, out, *flag);
}

__global__ __launch_bounds__(256) void transpose3_conv(const void* __restrict__ W0,
                                                       const void* __restrict__ W1,
                                                       const void* __restrict__ W2,
                                                       u16* __restrict__ out,
                                                       const int* __restrict__ flag) {
  const int z = blockIdx.z;
  const void* in = (z == 0) ? W0 : (z == 1) ? W1 : W2;
  tconv_body(in, out + (size_t)z * 2048 * 2048, *flag);
}

// ---------------------------------------------------------------------------
// GEMM r12 "g256f": r9's best structure (256-wide tile, 8 waves, 32 MFMA per
// barrier) + r10/r11's verified fragment-order LDS (0 bank conflicts) +
// 3-slot counted-vmcnt ring + hand-unrolled slots (no %3 VALU) + XCD swizzle.
//  - BN=256 (QKV): waves 2Mx4N, per-wave 128x64: MT=8,NT=4, 32 MFMA vs
//    12 ds_read_b128 per K-tile. LDS 96KB. Grid 16x24=384 (all co-resident
//    at 1 blk/CU... 1.5 rounds; acceptable, was r9's config at 168us).
//  - BN=128 (Wo): waves 4Mx2N, per-wave 64x64. LDS 72KB. Grid 16x16=256 =
//    exactly 1 block/CU, one full round (fixes r9's half-idle Wo).
//  - fragment-order: subtile st (16rx32c, 1KB) stored so read-lane l's frag
//    (row l&15, chunk l>>4) sits at st*1024 + l*16. Stage src = per-lane
//    global (verified r11); read = wave-linear contiguous -> 0 conflicts.
//  - ring distance 2: iter t stages t+2 (slot (t+2)%3, compile-time), reads
//    slot t%3; end-of-iter vmcnt(C) confirms t+1 (C = own-wave calls for one
//    tile; per-wave symmetric => barrier completes the cross-wave proof).
//    Loads stay in flight across 2 barriers; vmcnt(0) only in tail.
// ---------------------------------------------------------------------------
template <typename OutT, int BN>
__device__ __forceinline__ void g256f_core(const u16* __restrict__ A,
                                           const u16* __restrict__ Bt,
                                           OutT* __restrict__ C,
                                           int nwg, size_t bufStride) {
  constexpr int K = 2048;
  constexpr int WNW = (BN == 256) ? 4 : 2;  // wave cols
  constexpr int MT = (BN == 256) ? 8 : 4;   // per-wave M fragments
  constexpr int NT = 4;                     // per-wave N fragments
  __shared__ __align__(16) u16 Asl[3][256 * 32];
  __shared__ __align__(16) u16 Bsl[3][BN * 32];

  const int tid = threadIdx.x;
  const int lane = tid & 63, w = tid >> 6;  // 8 waves
  const int quad = lane >> 4, l15 = lane & 15;
  const int wm = w / WNW, wn = w % WNW;

  // XCD-chunked bijective swizzle (nwg: 384, 256 -- both %8==0, %16==0)
  const int q8 = nwg >> 3;
  const int id = (int)blockIdx.x;
  const int swz = (id & 7) * q8 + (id >> 3);
  const int m0 = (swz & 15) * 256;
  const int n0 = (swz >> 4) * BN;

  // fragment-order staging: wave w stages A subtiles {w, 8+w}, B {w[,8+w]}
  const u16* aS = A + (size_t)(m0 + w * 16 + l15) * K + quad * 8;
  const u16* bS = Bt + (size_t)(n0 + w * 16 + l15) * K + quad * 8;

  const f32x4 fz = {0.f, 0.f, 0.f, 0.f};
  f32x4 acc[MT][NT];
#pragma unroll
  for (int i = 0; i < MT; i++)
#pragma unroll
    for (int j = 0; j < NT; j++) acc[i][j] = fz;

  auto stagef = [&](int kidx, int sl) {
    const int kk = kidx * 32;
    gll16(aS + kk, &Asl[sl][w * 512]);
    gll16(aS + (size_t)128 * K + kk, &Asl[sl][(8 + w) * 512]);
    gll16(bS + kk, &Bsl[sl][w * 512]);
    if constexpr (BN == 256)
      gll16(bS + (size_t)128 * K + kk, &Bsl[sl][(8 + w) * 512]);
  };

  auto computef = [&](int sl) {
    bf16x8 afr[MT], bfr[NT];
#pragma unroll
    for (int mt = 0; mt < MT; mt++)
      afr[mt] = *(const bf16x8*)(&Asl[sl][(wm * MT + mt) * 512 + lane * 8]);
#pragma unroll
    for (int nt = 0; nt < NT; nt++)
      bfr[nt] = *(const bf16x8*)(&Bsl[sl][(wn * NT + nt) * 512 + lane * 8]);
    asm volatile("s_waitcnt lgkmcnt(0)" ::: "memory");
    __builtin_amdgcn_sched_barrier(0);
    __builtin_amdgcn_s_setprio(1);
#pragma unroll
    for (int mt = 0; mt < MT; mt++)
#pragma unroll
      for (int nt = 0; nt < NT; nt++)
        acc[mt][nt] = __builtin_amdgcn_mfma_f32_16x16x32_bf16(
            afr[mt], bfr[nt], acc[mt][nt], 0, 0, 0);
    __builtin_amdgcn_s_setprio(0);
  };

  // counted wait: C = per-wave gll16 calls per tile (literal immediates)
#define GVW()                                                                \
  do {                                                                       \
    if constexpr (BN == 256)                                                 \
      asm volatile("s_waitcnt vmcnt(4)" ::: "memory");                       \
    else                                                                     \
      asm volatile("s_waitcnt vmcnt(3)" ::: "memory");                       \
  } while (0)

  // prologue: stage tiles 0,1; confirm tile 0
  stagef(0, 0);
  stagef(1, 1);
  GVW();
  __builtin_amdgcn_s_barrier();

  // main: 64 K-tiles; 20 chunks of 3 (t=0..59) + 2 peeled (60,61)
  int t = 0;
#pragma unroll 1
  for (int c = 0; c < 20; ++c) {
    stagef(t + 2, 2); computef(0); GVW(); __builtin_amdgcn_s_barrier();
    stagef(t + 3, 0); computef(1); GVW(); __builtin_amdgcn_s_barrier();
    stagef(t + 4, 1); computef(2); GVW(); __builtin_amdgcn_s_barrier();
    t += 3;
  }
  stagef(62, 2); computef(0); GVW(); __builtin_amdgcn_s_barrier();  // t=60
  stagef(63, 0); computef(1); GVW(); __builtin_amdgcn_s_barrier();  // t=61
  computef(2);                                                      // t=62
  asm volatile("s_waitcnt vmcnt(0)" ::: "memory");
  __builtin_amdgcn_s_barrier();
  computef(0);                                                      // t=63
#undef GVW

  // epilogue: row = m0 + wm*(MT*16) + mt*16 + quad*4 + r;
  //           col = n0 + wn*64 + nt*16 + l15   (verified map)
#pragma unroll
  for (int mt = 0; mt < MT; mt++)
#pragma unroll
    for (int nt = 0; nt < NT; nt++) {
      const int colg = n0 + wn * 64 + nt * 16 + l15;
      const size_t cbase = (size_t)(colg >> 11) * bufStride + (colg & 2047);
#pragma unroll
      for (int r = 0; r < 4; r++) {
        const int row = m0 + wm * (MT * 16) + mt * 16 + quad * 4 + r;
        const float v = acc[mt][nt][r];
        if constexpr (sizeof(OutT) == 2)
          C[cbase + (size_t)row * 2048] = f2b(v);
        else
          C[cbase + (size_t)row * 2048] = v;
      }
    }
}

__global__ __launch_bounds__(512, 1) void g256f_bf(const u16* __restrict__ A,
                                                   const u16* __restrict__ Bt,
                                                   u16* __restrict__ C,
                                                   int nwg, size_t bufStride) {
  g256f_core<u16, 256>(A, Bt, C, nwg, bufStride);
}
__global__ __launch_bounds__(512, 1) void g256f_f32(const u16* __restrict__ A,
                                                    const u16* __restrict__ Bt,
                                                    float* __restrict__ C,
                                                    int nwg, size_t bufStride) {
  g256f_core<float, 128>(A, Bt, C, nwg, bufStride);
}

// ---------------------------------------------------------------------------
// V (B,L,H,Dh) -> Vt (B,H,Dh,L)
// ---------------------------------------------------------------------------
__global__ __launch_bounds__(256) void transpose_v_k(const u16* __restrict__ V,
                                                     u16* __restrict__ Vt) {
  __shared__ __align__(16) u16 tile[64][65];
  const int z = blockIdx.z;
  const int b = z >> 4, h = z & 15;
  const int l0 = blockIdx.y * 64, d0 = blockIdx.x * 64;
  const int tc = threadIdx.x & 63, tr4 = threadIdx.x >> 6;
#pragma unroll
  for (int p = 0; p < 16; p++) {
    int l = tr4 + p * 4;
    tile[l][tc] = V[(size_t)((b * Lc + l0 + l) * Hc + h) * DhC + d0 + tc];
  }
  __syncthreads();
#pragma unroll
  for (int p = 0; p < 16; p++) {
    int dd = tr4 + p * 4;
    Vt[((size_t)z * DhC + d0 + dd) * Lc + l0 + tc] = tile[tc][dd];
  }
}

// ---------------------------------------------------------------------------
// RoPE in place on Q and K; Q additionally scaled by 1/sqrt(Dh).
// One thread per (l,h,j), batch loop inside; exp2f (native v_exp_f32).
// ---------------------------------------------------------------------------
__global__ __launch_bounds__(256) void rope_qk(u16* __restrict__ Q, u16* __restrict__ K) {
  const int idx = blockIdx.x * 256 + threadIdx.x;  // (l, h, j)
  const int j = idx & 63;
  const int h = (idx >> 6) & 15;
  const int l = idx >> 10;
  const float inv = exp2f(-0.2958057561f * (float)j);  // theta^(-j/64)
  const float ang = (float)l * inv;
  float s, c;
  sincosf(ang, &s, &c);
  const float sc = 0.08838834764f;  // 1/sqrt(128)
#pragma unroll
  for (int b = 0; b < Bb; b++) {
    const size_t off = ((size_t)((b * Lc + l) * Hc + h)) * DhC + 2 * j;
    const float q0 = b2f(Q[off]), q1 = b2f(Q[off + 1]);
    const float k0 = b2f(K[off]), k1 = b2f(K[off + 1]);
    Q[off]     = f2b((q0 * c - q1 * s) * sc);
    Q[off + 1] = f2b((q1 * c + q0 * s) * sc);
    K[off]     = f2b(k0 * c - k1 * s);
    K[off + 1] = f2b(k1 * c + k0 * s);
  }
}

// ---------------------------------------------------------------------------
// Flash attention (causal), unchanged from passing round-1 version.
// ---------------------------------------------------------------------------
#define NEGBIG (-3.0e30f)
__global__ __launch_bounds__(256, 2) void flash_attn(const u16* __restrict__ Q,
                                                     const u16* __restrict__ Kg,
                                                     const u16* __restrict__ Vt,
                                                     u16* __restrict__ O) {
  __shared__ __align__(16) u16 Ks[2][64 * 128];
  __shared__ __align__(16) u16 Vs[2][128 * 64];
  const int tid = threadIdx.x;
  const int lane = tid & 63, w = tid >> 6;
  const int l31 = lane & 31, hib = lane >> 5;
  const int bh = blockIdx.y;
  const int b = bh >> 4, h = bh & 15;
  const int qt = (bh & 16) ? (int)blockIdx.x : (15 - (int)blockIdx.x);
  const int q0 = qt * 128;
  const int qw0 = q0 + w * 32;
  const int nkv = 2 * qt + 2;

  const int krl = lane >> 4, ksl = lane & 15;
  const int vrl = lane >> 3, vsl = lane & 7;

  bf16x8 qf[8];
  {
    const u16* qptr = Q + ((size_t)(b * Lc + qw0 + l31) * Hc + h) * DhC + 8 * hib;
#pragma unroll
    for (int s = 0; s < 8; s++) qf[s] = *(const bf16x8*)(qptr + s * 16);
  }

  {
#pragma unroll
    for (int p = 0; p < 4; p++) {
      const int r = p * 16 + w * 4 + krl;
      const int c = ksl ^ (r & 15);
      gll16(Kg + ((size_t)(b * Lc + r) * Hc + h) * DhC + c * 8,
            &Ks[0][(p * 256 + w * 64) * 8]);
    }
#pragma unroll
    for (int p = 0; p < 4; p++) {
      const int r = p * 32 + w * 8 + vrl;
      const int c = vsl ^ (r & 7);
      gll16(Vt + ((size_t)bh * DhC + r) * Lc + c * 8,
            &Vs[0][(p * 256 + w * 64) * 8]);
    }
  }

  f32x16 o[4];
#pragma unroll
  for (int dt = 0; dt < 4; dt++) o[dt] = (f32x16)0.0f;
  float mrow = NEGBIG, lrow = 0.f;

  __syncthreads();

  for (int kvt = 0; kvt < nkv; kvt++) {
    const int cur = kvt & 1;
    const u16* Ksc = Ks[cur];
    const u16* Vsc = Vs[cur];

    if (kvt + 1 < nkv) {
      const int nv0 = (kvt + 1) * 64;
      const int nxt = cur ^ 1;
#pragma unroll
      for (int p = 0; p < 4; p++) {
        const int r = p * 16 + w * 4 + krl;
        const int c = ksl ^ (r & 15);
        gll16(Kg + ((size_t)(b * Lc + nv0 + r) * Hc + h) * DhC + c * 8,
              &Ks[nxt][(p * 256 + w * 64) * 8]);
      }
#pragma unroll
      for (int p = 0; p < 4; p++) {
        const int r = p * 32 + w * 8 + vrl;
        const int c = vsl ^ (r & 7);
        gll16(Vt + ((size_t)bh * DhC + r) * Lc + nv0 + c * 8,
              &Vs[nxt][(p * 256 + w * 64) * 8]);
      }
    }

    const int kv0 = kvt * 64;
    const bool active = (kv0 <= qw0 + 31);
    if (active) {
      f32x16 s0 = (f32x16)0.0f, s1 = (f32x16)0.0f;
      __builtin_amdgcn_s_setprio(1);
#pragma unroll
      for (int s = 0; s < 8; s++) {
        const int ch = ((2 * s + hib) ^ (l31 & 15)) * 8;
        bf16x8 k0 = *(const bf16x8*)(&Ksc[l31 * 128 + ch]);
        bf16x8 k1 = *(const bf16x8*)(&Ksc[(32 + l31) * 128 + ch]);
        s0 = __builtin_amdgcn_mfma_f32_32x32x16_bf16(k0, qf[s], s0, 0, 0, 0);
        s1 = __builtin_amdgcn_mfma_f32_32x32x16_bf16(k1, qf[s], s1, 0, 0, 0);
      }
      __builtin_amdgcn_s_setprio(0);

      if (kv0 + 63 > qw0) {
        const int qg = qw0 + l31;
#pragma unroll
        for (int r = 0; r < 16; r++) {
          const int cr = (r & 3) + 8 * (r >> 2) + 4 * hib;
          if (kv0 + cr > qg) s0[r] = NEGBIG;
          if (kv0 + 32 + cr > qg) s1[r] = NEGBIG;
        }
      }

      float mx;
      {
        float a[8];
#pragma unroll
        for (int i = 0; i < 8; i++)
          a[i] = fmaxf(fmaxf(s0[i], s0[i + 8]), fmaxf(s1[i], s1[i + 8]));
        float b0 = fmaxf(a[0], a[4]), b1 = fmaxf(a[1], a[5]);
        float b2 = fmaxf(a[2], a[6]), b3 = fmaxf(a[3], a[7]);
        mx = fmaxf(fmaxf(b0, b1), fmaxf(b2, b3));
      }
      mx = fmaxf(mx, __shfl_xor(mx, 32, 64));

      if (!__all(mx - mrow <= 8.f)) {
        const float mnew = fmaxf(mrow, mx);
        const float al = __expf(mrow - mnew);
#pragma unroll
        for (int dt = 0; dt < 4; dt++)
#pragma unroll
          for (int e = 0; e < 16; e++) o[dt][e] *= al;
        lrow *= al;
        mrow = mnew;
      }

#pragma unroll
      for (int i = 0; i < 16; i++) {
        s0[i] = __expf(s0[i] - mrow);
        s1[i] = __expf(s1[i] - mrow);
      }
      float sm;
      {
        float a[8];
#pragma unroll
        for (int i = 0; i < 8; i++)
          a[i] = (s0[i] + s0[i + 8]) + (s1[i] + s1[i + 8]);
        sm = ((a[0] + a[4]) + (a[1] + a[5])) + ((a[2] + a[6]) + (a[3] + a[7]));
      }
      sm += __shfl_xor(sm, 32, 64);
      lrow += sm;

      bf16x8 paf[4];
#pragma unroll
      for (int t = 0; t < 2; t++) {
#pragma unroll
        for (int h8 = 0; h8 < 2; h8++) {
          const int rB = 8 * h8;
          u32 lo0, lo1, hi0, hi1;
          if (t == 0) {
            lo0 = cvtpk(s0[rB + 0], s0[rB + 1]);
            lo1 = cvtpk(s0[rB + 2], s0[rB + 3]);
            hi0 = cvtpk(s0[rB + 4], s0[rB + 5]);
            hi1 = cvtpk(s0[rB + 6], s0[rB + 7]);
          } else {
            lo0 = cvtpk(s1[rB + 0], s1[rB + 1]);
            lo1 = cvtpk(s1[rB + 2], s1[rB + 3]);
            hi0 = cvtpk(s1[rB + 4], s1[rB + 5]);
            hi1 = cvtpk(s1[rB + 6], s1[rB + 7]);
          }
          const u32 g0 = hib ? lo0 : hi0;
          const u32 g1 = hib ? lo1 : hi1;
          const u32 r0 = (u32)__shfl_xor((int)g0, 32, 64);
          const u32 r1 = (u32)__shfl_xor((int)g1, 32, 64);
          union { u32 u[4]; bf16x8 v; } pu;
          pu.u[0] = hib ? r0 : lo0;
          pu.u[1] = hib ? r1 : lo1;
          pu.u[2] = hib ? hi0 : r0;
          pu.u[3] = hib ? hi1 : r1;
          paf[2 * t + h8] = pu.v;
        }
      }

      __builtin_amdgcn_s_setprio(1);
#pragma unroll
      for (int B = 0; B < 4; B++) {
#pragma unroll
        for (int dt = 0; dt < 4; dt++) {
          const bf16x8 vf = *(const bf16x8*)(
              &Vsc[(32 * dt + l31) * 64 + (((2 * B + hib) ^ (l31 & 7))) * 8]);
          o[dt] = __builtin_amdgcn_mfma_f32_32x32x16_bf16(paf[B], vf, o[dt], 0, 0, 0);
        }
      }
      __builtin_amdgcn_s_setprio(0);
    }

    __syncthreads();
  }

#pragma unroll
  for (int r = 0; r < 16; r++) {
    const int cr = (r & 3) + 8 * (r >> 2) + 4 * hib;
    const float linv = 1.0f / __shfl(lrow, cr, 64);
    const size_t rowoff = ((size_t)(b * Lc + qw0 + cr) * Hc + h) * DhC + l31;
#pragma unroll
    for (int dt = 0; dt < 4; dt++)
      O[rowoff + 32 * dt] = f2b(o[dt][r] * linv);
  }
}

// ---------------------------------------------------------------------------
// ws layout (72 MiB + 256 B peak), serial weight-slot reuse:
//   [0,256) flag | WT 8MiB (Wo only) | xc 16MiB | Qb 16MiB | Kb 16MiB | Vb 16MiB
//   Qb,Kb,Vb contiguous (fused-QKV gemm writes via (col>>11)*XSZ).
//   WTall (24MiB, 3 transposed QKV weights) lives in d_out-as-scratch
//   (32MiB, fully overwritten by the final gemm). Vtb aliases xc; Ob aliases Vb.
// ---------------------------------------------------------------------------
extern "C" void kernel_launch(void* const* d_in, const int* in_sizes, int n_in,
                              void* d_out, int out_size, void* d_ws, size_t ws_size,
                              hipStream_t stream) {
  const void* x  = d_in[0];
  const void* Wq = d_in[1];
  const void* Wk = d_in[2];
  const void* Wv = d_in[3];
  const void* Wo = d_in[4];
  float* out = (float*)d_out;   // reference output dtype: float32 (verified r4)

  char* w = (char*)d_ws;
  const size_t WSZ = (size_t)2048 * 2048;
  const size_t XSZ = (size_t)Bb * Lc * Dc;
  int* flag = (int*)w;
  u16* WT  = (u16*)(w + 256);
  u16* xc  = WT + WSZ;
  u16* Qb  = xc + XSZ;
  u16* Kb  = Qb + XSZ;
  u16* Vb  = Kb + XSZ;
  u16* Vtb = xc;
  u16* Ob  = Vb;
  u16* WTall = (u16*)d_out;   // 24 MiB scratch inside the 32 MiB output

  sniff_dtype<<<1, 256, 0, stream>>>((const u16*)x, flag);
  conv_x<<<(int)(XSZ / 1024), 256, 0, stream>>>(x, xc, flag);

  // all three QKV weight transposes in one dispatch
  transpose3_conv<<<dim3(32, 32, 3), 256, 0, stream>>>(Wq, Wk, Wv, WTall, flag);

  // fused QKV: C[4096, 6144] = xc @ [Wq|Wk|Wv]^T -> Qb/Kb/Vb via col>>11
  g256f_bf<<<dim3(384), 512, 0, stream>>>(xc, WTall, Qb, 384, XSZ);

  rope_qk<<<(Lc * Hc * 64) / 256, 256, 0, stream>>>(Qb, Kb);

  dim3 vgrid(2, 32, 32);
  transpose_v_k<<<vgrid, 256, 0, stream>>>(Vb, Vtb);

  dim3 fgrid(16, 32);
  flash_attn<<<fgrid, 256, 0, stream>>>(Qb, Kb, Vtb, Ob);

  dim3 tgrid(32, 32);
  transpose2d_conv<<<tgrid, 256, 0, stream>>>(Wo, WT, flag);
  g256f_f32<<<dim3(256), 512, 0, stream>>>(Ob, WT, out, 256, 0);
}

// Round 7
// 528.439 us; speedup vs baseline: 1.1624x; 1.0050x over previous
//
#include <hip/hip_runtime.h>

typedef unsigned short u16;
typedef unsigned int u32;

#define Bb 2
#define Lc 2048
#define Dc 2048
#define Hc 16
#define DhC 128

typedef __bf16 bf16x8 __attribute__((ext_vector_type(8)));
typedef float f32x4 __attribute__((ext_vector_type(4)));
typedef float f32x16 __attribute__((ext_vector_type(16)));

__device__ __forceinline__ u16 f2b(float f) {
  u32 u = __float_as_uint(f);
  u32 r = (u + 0x7fffu + ((u >> 16) & 1u)) >> 16;
  return (u16)r;
}
__device__ __forceinline__ float b2f(u16 u) {
  return __uint_as_float(((u32)u) << 16);
}

// pack 2 f32 -> 1 u32 of 2 bf16 (lo in low half) -- T12 recipe, no builtin
__device__ __forceinline__ u32 cvtpk(float lo, float hi) {
  u32 r;
  asm("v_cvt_pk_bf16_f32 %0, %1, %2" : "=v"(r) : "v"(lo), "v"(hi));
  return r;
}

// async global->LDS DMA, 16B/lane; LDS dest = wave-uniform base + lane*16
__device__ __forceinline__ void gll16(const void* g, void* l) {
  __builtin_amdgcn_global_load_lds(
      (const __attribute__((address_space(1))) u32*)g,
      (__attribute__((address_space(3))) u32*)l, 16, 0, 0);
}

// ---------------------------------------------------------------------------
// Dtype sniffer + x canonicalize (kept; inputs verified bf16-compatible r4).
// ---------------------------------------------------------------------------
__global__ __launch_bounds__(256) void sniff_dtype(const u16* __restrict__ x,
                                                   int* __restrict__ flag) {
  __shared__ int bad;
  if (threadIdx.x == 0) bad = 0;
  __syncthreads();
  int local = 0;
  for (int i = threadIdx.x; i < 65536; i += 256) {
    float v = fabsf(b2f(x[i]));
    if (!(v < 1000.f)) local = 1;
  }
  if (local) atomicOr(&bad, 1);
  __syncthreads();
  if (threadIdx.x == 0) *flag = bad;
}

__global__ __launch_bounds__(256) void conv_x(const void* __restrict__ in,
                                              u16* __restrict__ out,
                                              const int* __restrict__ flag) {
  const int f32 = *flag;
  const int i0 = (blockIdx.x * 256 + threadIdx.x) * 4;
  if (f32) {
    const float* p = (const float*)in;
#pragma unroll
    for (int j = 0; j < 4; j++) out[i0 + j] = f2b(p[i0 + j]);
  } else {
    const u16* p = (const u16*)in;
#pragma unroll
    for (int j = 0; j < 4; j++) out[i0 + j] = p[i0 + j];
  }
}

// ---------------------------------------------------------------------------
// 2048x2048 transpose with dtype conversion (weights -> bf16 W^T).
// transpose3_conv: z-indexed fused variant for the 3 QKV weights.
// ---------------------------------------------------------------------------
__device__ __forceinline__ void tconv_body(const void* in, u16* out, int f32) {
  __shared__ __align__(16) u16 tile[64][65];
  const int r0 = blockIdx.y * 64, c0 = blockIdx.x * 64;
  const int tc = threadIdx.x & 63, tr4 = threadIdx.x >> 6;
#pragma unroll
  for (int p = 0; p < 16; p++) {
    int r = tr4 + p * 4;
    size_t idx = (size_t)(r0 + r) * 2048 + c0 + tc;
    tile[r][tc] = f32 ? f2b(((const float*)in)[idx]) : ((const u16*)in)[idx];
  }
  __syncthreads();
#pragma unroll
  for (int p = 0; p < 16; p++) {
    int rr = tr4 + p * 4;
    out[(size_t)(c0 + rr) * 2048 + r0 + tc] = tile[tc][rr];
  }
}

__global__ __launch_bounds__(256) void transpose2d_conv(const void* __restrict__ in,
                                                        u16* __restrict__ out,
                                                        const int* __restrict__ flag) {
  tconv_body(in, out, *flag);
}

__global__ __launch_bounds__(256) void transpose3_conv(const void* __restrict__ W0,
                                                       const void* __restrict__ W1,
                                                       const void* __restrict__ W2,
                                                       u16* __restrict__ out,
                                                       const int* __restrict__ flag) {
  const int z = blockIdx.z;
  const void* in = (z == 0) ? W0 : (z == 1) ? W1 : W2;
  tconv_body(in, out + (size_t)z * 2048 * 2048, *flag);
}

// ---------------------------------------------------------------------------
// GEMM r13 "g256f": r12 ring (3-slot, counted vmcnt, fragment-order LDS,
// 0 conflicts) + SPLIT COMPUTE CLUSTER with counted lgkmcnt:
//   issue reads [B x4 | A-lo x4] , sched_barrier, [A-hi x4];
//   lgkmcnt(4) -> 16 MFMA(lo) ; lgkmcnt(0) -> 16 MFMA(hi).
//   A-hi read latency hides under MFMA(lo); post-barrier LDS burst halved.
// + FUSED V-TRANSPOSE epilogue (FUSEV): output cols >= 4096 are V -> written
//   directly as Vt (B,H,Dh,L). acc rows are 4 consecutive l -> 8B-contiguous
//   per-lane stores. Kills the transpose_v_k dispatch (64 MB traffic).
// ---------------------------------------------------------------------------
template <typename OutT, int BN, bool FUSEV>
__device__ __forceinline__ void g256f_core(const u16* __restrict__ A,
                                           const u16* __restrict__ Bt,
                                           OutT* __restrict__ C,
                                           u16* __restrict__ Vt,
                                           int nwg, size_t bufStride) {
  constexpr int K = 2048;
  constexpr int WNW = (BN == 256) ? 4 : 2;  // wave cols
  constexpr int MT = (BN == 256) ? 8 : 4;   // per-wave M fragments
  constexpr int NT = 4;                     // per-wave N fragments
  __shared__ __align__(16) u16 Asl[3][256 * 32];
  __shared__ __align__(16) u16 Bsl[3][BN * 32];

  const int tid = threadIdx.x;
  const int lane = tid & 63, w = tid >> 6;  // 8 waves
  const int quad = lane >> 4, l15 = lane & 15;
  const int wm = w / WNW, wn = w % WNW;

  // XCD-chunked bijective swizzle (nwg: 384, 256 -- both %8==0)
  const int q8 = nwg >> 3;
  const int id = (int)blockIdx.x;
  const int swz = (id & 7) * q8 + (id >> 3);
  const int m0 = (swz & 15) * 256;
  const int n0 = (swz >> 4) * BN;

  // fragment-order staging: wave w stages A subtiles {w, 8+w}, B {w[,8+w]}
  const u16* aS = A + (size_t)(m0 + w * 16 + l15) * K + quad * 8;
  const u16* bS = Bt + (size_t)(n0 + w * 16 + l15) * K + quad * 8;

  const f32x4 fz = {0.f, 0.f, 0.f, 0.f};
  f32x4 acc[MT][NT];
#pragma unroll
  for (int i = 0; i < MT; i++)
#pragma unroll
    for (int j = 0; j < NT; j++) acc[i][j] = fz;

  auto stagef = [&](int kidx, int sl) {
    const int kk = kidx * 32;
    gll16(aS + kk, &Asl[sl][w * 512]);
    gll16(aS + (size_t)128 * K + kk, &Asl[sl][(8 + w) * 512]);
    gll16(bS + kk, &Bsl[sl][w * 512]);
    if constexpr (BN == 256)
      gll16(bS + (size_t)128 * K + kk, &Bsl[sl][(8 + w) * 512]);
  };

  auto computef = [&](int sl) {
    bf16x8 afr[MT], bfr[NT];
    // group 1: all B frags + low half of A frags
#pragma unroll
    for (int nt = 0; nt < NT; nt++)
      bfr[nt] = *(const bf16x8*)(&Bsl[sl][(wn * NT + nt) * 512 + lane * 8]);
#pragma unroll
    for (int mt = 0; mt < MT / 2; mt++)
      afr[mt] = *(const bf16x8*)(&Asl[sl][(wm * MT + mt) * 512 + lane * 8]);
    __builtin_amdgcn_sched_barrier(0);  // pin group-1 issue order
    // group 2: high half of A frags (latency hidden under MFMA lo)
#pragma unroll
    for (int mt = MT / 2; mt < MT; mt++)
      afr[mt] = *(const bf16x8*)(&Asl[sl][(wm * MT + mt) * 512 + lane * 8]);
    if constexpr (MT == 8)
      asm volatile("s_waitcnt lgkmcnt(4)" ::: "memory");
    else
      asm volatile("s_waitcnt lgkmcnt(2)" ::: "memory");
    __builtin_amdgcn_sched_barrier(0);
    __builtin_amdgcn_s_setprio(1);
#pragma unroll
    for (int mt = 0; mt < MT / 2; mt++)
#pragma unroll
      for (int nt = 0; nt < NT; nt++)
        acc[mt][nt] = __builtin_amdgcn_mfma_f32_16x16x32_bf16(
            afr[mt], bfr[nt], acc[mt][nt], 0, 0, 0);
    asm volatile("s_waitcnt lgkmcnt(0)" ::: "memory");
    __builtin_amdgcn_sched_barrier(0);
#pragma unroll
    for (int mt = MT / 2; mt < MT; mt++)
#pragma unroll
      for (int nt = 0; nt < NT; nt++)
        acc[mt][nt] = __builtin_amdgcn_mfma_f32_16x16x32_bf16(
            afr[mt], bfr[nt], acc[mt][nt], 0, 0, 0);
    __builtin_amdgcn_s_setprio(0);
  };

  // counted wait: C = per-wave gll16 calls per tile (literal immediates)
#define GVW()                                                                \
  do {                                                                       \
    if constexpr (BN == 256)                                                 \
      asm volatile("s_waitcnt vmcnt(4)" ::: "memory");                       \
    else                                                                     \
      asm volatile("s_waitcnt vmcnt(3)" ::: "memory");                       \
  } while (0)

  // prologue: stage tiles 0,1; confirm tile 0
  stagef(0, 0);
  stagef(1, 1);
  GVW();
  __builtin_amdgcn_s_barrier();

  // main: 64 K-tiles; 20 chunks of 3 (t=0..59) + 2 peeled (60,61)
  int t = 0;
#pragma unroll 1
  for (int c = 0; c < 20; ++c) {
    stagef(t + 2, 2); computef(0); GVW(); __builtin_amdgcn_s_barrier();
    stagef(t + 3, 0); computef(1); GVW(); __builtin_amdgcn_s_barrier();
    stagef(t + 4, 1); computef(2); GVW(); __builtin_amdgcn_s_barrier();
    t += 3;
  }
  stagef(62, 2); computef(0); GVW(); __builtin_amdgcn_s_barrier();  // t=60
  stagef(63, 0); computef(1); GVW(); __builtin_amdgcn_s_barrier();  // t=61
  computef(2);                                                      // t=62
  asm volatile("s_waitcnt vmcnt(0)" ::: "memory");
  __builtin_amdgcn_s_barrier();
  computef(0);                                                      // t=63
#undef GVW

  // epilogue: row = m0 + wm*(MT*16) + mt*16 + quad*4 + r;
  //           col = n0 + wn*64 + nt*16 + l15   (verified map)
#pragma unroll
  for (int mt = 0; mt < MT; mt++)
#pragma unroll
    for (int nt = 0; nt < NT; nt++) {
      const int colg = n0 + wn * 64 + nt * 16 + l15;
      const int row0 = m0 + wm * (MT * 16) + mt * 16 + quad * 4;
      if (FUSEV && (colg >> 11) == 2) {
        // V: write directly transposed (B,H,Dh,L). rows are consecutive l.
        const int hd = colg & 2047;  // h*128 + d
        const int bb = row0 >> 11, ll = row0 & 2047;
        const size_t off =
            (((size_t)(bb * 16 + (hd >> 7))) * 128 + (hd & 127)) * 2048 + ll;
#pragma unroll
        for (int r = 0; r < 4; r++) Vt[off + r] = f2b(acc[mt][nt][r]);
      } else {
        const size_t cbase =
            (size_t)(colg >> 11) * bufStride + (colg & 2047);
#pragma unroll
        for (int r = 0; r < 4; r++) {
          const float v = acc[mt][nt][r];
          if constexpr (sizeof(OutT) == 2)
            C[cbase + (size_t)(row0 + r) * 2048] = f2b(v);
          else
            C[cbase + (size_t)(row0 + r) * 2048] = v;
        }
      }
    }
}

__global__ __launch_bounds__(512, 1) void g256f_bf(const u16* __restrict__ A,
                                                   const u16* __restrict__ Bt,
                                                   u16* __restrict__ C,
                                                   u16* __restrict__ Vt,
                                                   int nwg, size_t bufStride) {
  g256f_core<u16, 256, true>(A, Bt, C, Vt, nwg, bufStride);
}
__global__ __launch_bounds__(512, 1) void g256f_f32(const u16* __restrict__ A,
                                                    const u16* __restrict__ Bt,
                                                    float* __restrict__ C,
                                                    int nwg, size_t bufStride) {
  g256f_core<float, 128, false>(A, Bt, C, nullptr, nwg, bufStride);
}

// ---------------------------------------------------------------------------
// RoPE in place on Q and K; Q additionally scaled by 1/sqrt(Dh).
// One thread per (l,h,j), batch loop inside; exp2f (native v_exp_f32).
// ---------------------------------------------------------------------------
__global__ __launch_bounds__(256) void rope_qk(u16* __restrict__ Q, u16* __restrict__ K) {
  const int idx = blockIdx.x * 256 + threadIdx.x;  // (l, h, j)
  const int j = idx & 63;
  const int h = (idx >> 6) & 15;
  const int l = idx >> 10;
  const float inv = exp2f(-0.2958057561f * (float)j);  // theta^(-j/64)
  const float ang = (float)l * inv;
  float s, c;
  sincosf(ang, &s, &c);
  const float sc = 0.08838834764f;  // 1/sqrt(128)
#pragma unroll
  for (int b = 0; b < Bb; b++) {
    const size_t off = ((size_t)((b * Lc + l) * Hc + h)) * DhC + 2 * j;
    const float q0 = b2f(Q[off]), q1 = b2f(Q[off + 1]);
    const float k0 = b2f(K[off]), k1 = b2f(K[off + 1]);
    Q[off]     = f2b((q0 * c - q1 * s) * sc);
    Q[off + 1] = f2b((q1 * c + q0 * s) * sc);
    K[off]     = f2b(k0 * c - k1 * s);
    K[off + 1] = f2b(k1 * c + k0 * s);
  }
}

// ---------------------------------------------------------------------------
// Flash attention (causal), unchanged from passing round-1 version.
// ---------------------------------------------------------------------------
#define NEGBIG (-3.0e30f)
__global__ __launch_bounds__(256, 2) void flash_attn(const u16* __restrict__ Q,
                                                     const u16* __restrict__ Kg,
                                                     const u16* __restrict__ Vt,
                                                     u16* __restrict__ O) {
  __shared__ __align__(16) u16 Ks[2][64 * 128];
  __shared__ __align__(16) u16 Vs[2][128 * 64];
  const int tid = threadIdx.x;
  const int lane = tid & 63, w = tid >> 6;
  const int l31 = lane & 31, hib = lane >> 5;
  const int bh = blockIdx.y;
  const int b = bh >> 4, h = bh & 15;
  const int qt = (bh & 16) ? (int)blockIdx.x : (15 - (int)blockIdx.x);
  const int q0 = qt * 128;
  const int qw0 = q0 + w * 32;
  const int nkv = 2 * qt + 2;

  const int krl = lane >> 4, ksl = lane & 15;
  const int vrl = lane >> 3, vsl = lane & 7;

  bf16x8 qf[8];
  {
    const u16* qptr = Q + ((size_t)(b * Lc + qw0 + l31) * Hc + h) * DhC + 8 * hib;
#pragma unroll
    for (int s = 0; s < 8; s++) qf[s] = *(const bf16x8*)(qptr + s * 16);
  }

  {
#pragma unroll
    for (int p = 0; p < 4; p++) {
      const int r = p * 16 + w * 4 + krl;
      const int c = ksl ^ (r & 15);
      gll16(Kg + ((size_t)(b * Lc + r) * Hc + h) * DhC + c * 8,
            &Ks[0][(p * 256 + w * 64) * 8]);
    }
#pragma unroll
    for (int p = 0; p < 4; p++) {
      const int r = p * 32 + w * 8 + vrl;
      const int c = vsl ^ (r & 7);
      gll16(Vt + ((size_t)bh * DhC + r) * Lc + c * 8,
            &Vs[0][(p * 256 + w * 64) * 8]);
    }
  }

  f32x16 o[4];
#pragma unroll
  for (int dt = 0; dt < 4; dt++) o[dt] = (f32x16)0.0f;
  float mrow = NEGBIG, lrow = 0.f;

  __syncthreads();

  for (int kvt = 0; kvt < nkv; kvt++) {
    const int cur = kvt & 1;
    const u16* Ksc = Ks[cur];
    const u16* Vsc = Vs[cur];

    if (kvt + 1 < nkv) {
      const int nv0 = (kvt + 1) * 64;
      const int nxt = cur ^ 1;
#pragma unroll
      for (int p = 0; p < 4; p++) {
        const int r = p * 16 + w * 4 + krl;
        const int c = ksl ^ (r & 15);
        gll16(Kg + ((size_t)(b * Lc + nv0 + r) * Hc + h) * DhC + c * 8,
              &Ks[nxt][(p * 256 + w * 64) * 8]);
      }
#pragma unroll
      for (int p = 0; p < 4; p++) {
        const int r = p * 32 + w * 8 + vrl;
        const int c = vsl ^ (r & 7);
        gll16(Vt + ((size_t)bh * DhC + r) * Lc + nv0 + c * 8,
              &Vs[nxt][(p * 256 + w * 64) * 8]);
      }
    }

    const int kv0 = kvt * 64;
    const bool active = (kv0 <= qw0 + 31);
    if (active) {
      f32x16 s0 = (f32x16)0.0f, s1 = (f32x16)0.0f;
      __builtin_amdgcn_s_setprio(1);
#pragma unroll
      for (int s = 0; s < 8; s++) {
        const int ch = ((2 * s + hib) ^ (l31 & 15)) * 8;
        bf16x8 k0 = *(const bf16x8*)(&Ksc[l31 * 128 + ch]);
        bf16x8 k1 = *(const bf16x8*)(&Ksc[(32 + l31) * 128 + ch]);
        s0 = __builtin_amdgcn_mfma_f32_32x32x16_bf16(k0, qf[s], s0, 0, 0, 0);
        s1 = __builtin_amdgcn_mfma_f32_32x32x16_bf16(k1, qf[s], s1, 0, 0, 0);
      }
      __builtin_amdgcn_s_setprio(0);

      if (kv0 + 63 > qw0) {
        const int qg = qw0 + l31;
#pragma unroll
        for (int r = 0; r < 16; r++) {
          const int cr = (r & 3) + 8 * (r >> 2) + 4 * hib;
          if (kv0 + cr > qg) s0[r] = NEGBIG;
          if (kv0 + 32 + cr > qg) s1[r] = NEGBIG;
        }
      }

      float mx;
      {
        float a[8];
#pragma unroll
        for (int i = 0; i < 8; i++)
          a[i] = fmaxf(fmaxf(s0[i], s0[i + 8]), fmaxf(s1[i], s1[i + 8]));
        float b0 = fmaxf(a[0], a[4]), b1 = fmaxf(a[1], a[5]);
        float b2 = fmaxf(a[2], a[6]), b3 = fmaxf(a[3], a[7]);
        mx = fmaxf(fmaxf(b0, b1), fmaxf(b2, b3));
      }
      mx = fmaxf(mx, __shfl_xor(mx, 32, 64));

      if (!__all(mx - mrow <= 8.f)) {
        const float mnew = fmaxf(mrow, mx);
        const float al = __expf(mrow - mnew);
#pragma unroll
        for (int dt = 0; dt < 4; dt++)
#pragma unroll
          for (int e = 0; e < 16; e++) o[dt][e] *= al;
        lrow *= al;
        mrow = mnew;
      }

#pragma unroll
      for (int i = 0; i < 16; i++) {
        s0[i] = __expf(s0[i] - mrow);
        s1[i] = __expf(s1[i] - mrow);
      }
      float sm;
      {
        float a[8];
#pragma unroll
        for (int i = 0; i < 8; i++)
          a[i] = (s0[i] + s0[i + 8]) + (s1[i] + s1[i + 8]);
        sm = ((a[0] + a[4]) + (a[1] + a[5])) + ((a[2] + a[6]) + (a[3] + a[7]));
      }
      sm += __shfl_xor(sm, 32, 64);
      lrow += sm;

      bf16x8 paf[4];
#pragma unroll
      for (int t = 0; t < 2; t++) {
#pragma unroll
        for (int h8 = 0; h8 < 2; h8++) {
          const int rB = 8 * h8;
          u32 lo0, lo1, hi0, hi1;
          if (t == 0) {
            lo0 = cvtpk(s0[rB + 0], s0[rB + 1]);
            lo1 = cvtpk(s0[rB + 2], s0[rB + 3]);
            hi0 = cvtpk(s0[rB + 4], s0[rB + 5]);
            hi1 = cvtpk(s0[rB + 6], s0[rB + 7]);
          } else {
            lo0 = cvtpk(s1[rB + 0], s1[rB + 1]);
            lo1 = cvtpk(s1[rB + 2], s1[rB + 3]);
            hi0 = cvtpk(s1[rB + 4], s1[rB + 5]);
            hi1 = cvtpk(s1[rB + 6], s1[rB + 7]);
          }
          const u32 g0 = hib ? lo0 : hi0;
          const u32 g1 = hib ? lo1 : hi1;
          const u32 r0 = (u32)__shfl_xor((int)g0, 32, 64);
          const u32 r1 = (u32)__shfl_xor((int)g1, 32, 64);
          union { u32 u[4]; bf16x8 v; } pu;
          pu.u[0] = hib ? r0 : lo0;
          pu.u[1] = hib ? r1 : lo1;
          pu.u[2] = hib ? hi0 : r0;
          pu.u[3] = hib ? hi1 : r1;
          paf[2 * t + h8] = pu.v;
        }
      }

      __builtin_amdgcn_s_setprio(1);
#pragma unroll
      for (int B = 0; B < 4; B++) {
#pragma unroll
        for (int dt = 0; dt < 4; dt++) {
          const bf16x8 vf = *(const bf16x8*)(
              &Vsc[(32 * dt + l31) * 64 + (((2 * B + hib) ^ (l31 & 7))) * 8]);
          o[dt] = __builtin_amdgcn_mfma_f32_32x32x16_bf16(paf[B], vf, o[dt], 0, 0, 0);
        }
      }
      __builtin_amdgcn_s_setprio(0);
    }

    __syncthreads();
  }

#pragma unroll
  for (int r = 0; r < 16; r++) {
    const int cr = (r & 3) + 8 * (r >> 2) + 4 * hib;
    const float linv = 1.0f / __shfl(lrow, cr, 64);
    const size_t rowoff = ((size_t)(b * Lc + qw0 + cr) * Hc + h) * DhC + l31;
#pragma unroll
    for (int dt = 0; dt < 4; dt++)
      O[rowoff + 32 * dt] = f2b(o[dt][r] * linv);
  }
}

// ---------------------------------------------------------------------------
// ws layout (72 MiB + 256 B peak):
//   [0,256) flag | WT 8MiB (Wo only) | xc 16MiB | Qb 16MiB | Kb 16MiB | Vt 16MiB
//   QKV gemm: reads xc + WTall(d_out); writes Qb, Kb (via col>>11) and V
//   DIRECTLY TRANSPOSED into Vt (old Vb slot). transpose_v_k eliminated.
//   Ob = xc (dead after QKV gemm). WTall dead after QKV gemm; final gemm
//   overwrites d_out.
// ---------------------------------------------------------------------------
extern "C" void kernel_launch(void* const* d_in, const int* in_sizes, int n_in,
                              void* d_out, int out_size, void* d_ws, size_t ws_size,
                              hipStream_t stream) {
  const void* x  = d_in[0];
  const void* Wq = d_in[1];
  const void* Wk = d_in[2];
  const void* Wv = d_in[3];
  const void* Wo = d_in[4];
  float* out = (float*)d_out;   // reference output dtype: float32 (verified r4)

  char* w = (char*)d_ws;
  const size_t WSZ = (size_t)2048 * 2048;
  const size_t XSZ = (size_t)Bb * Lc * Dc;
  int* flag = (int*)w;
  u16* WT  = (u16*)(w + 256);
  u16* xc  = WT + WSZ;
  u16* Qb  = xc + XSZ;
  u16* Kb  = Qb + XSZ;
  u16* Vtb = Kb + XSZ;   // V written directly transposed here (old Vb slot)
  u16* Ob  = xc;          // xc dead after QKV gemm
  u16* WTall = (u16*)d_out;   // 24 MiB scratch inside the 32 MiB output

  sniff_dtype<<<1, 256, 0, stream>>>((const u16*)x, flag);
  conv_x<<<(int)(XSZ / 1024), 256, 0, stream>>>(x, xc, flag);

  // all three QKV weight transposes in one dispatch
  transpose3_conv<<<dim3(32, 32, 3), 256, 0, stream>>>(Wq, Wk, Wv, WTall, flag);

  // fused QKV: C[4096, 6144] = xc @ [Wq|Wk|Wv]^T -> Qb/Kb via col>>11,
  // V directly transposed into Vtb
  g256f_bf<<<dim3(384), 512, 0, stream>>>(xc, WTall, Qb, Vtb, 384, XSZ);

  rope_qk<<<(Lc * Hc * 64) / 256, 256, 0, stream>>>(Qb, Kb);

  dim3 fgrid(16, 32);
  flash_attn<<<fgrid, 256, 0, stream>>>(Qb, Kb, Vtb, Ob);

  dim3 tgrid(32, 32);
  transpose2d_conv<<<tgrid, 256, 0, stream>>>(Wo, WT, flag);
  g256f_f32<<<dim3(256), 512, 0, stream>>>(Ob, WT, out, 256, 0);
}